// Round 1
// baseline (776.104 us; speedup 1.0000x reference)
//
#include <hip/hip_runtime.h>
#include <math.h>

#define N_NODES 50000
#define N_EDGES 262144

// ---------------------------------------------------------------------------
// CSR build kernels
// ---------------------------------------------------------------------------
__global__ void zero_int_kernel(int* p, int n) {
    int i = blockIdx.x * 256 + threadIdx.x;
    if (i < n) p[i] = 0;
}

__global__ void count_kernel(const int* __restrict__ dst, int* __restrict__ deg, int E) {
    int e = blockIdx.x * 256 + threadIdx.x;
    if (e < E) atomicAdd(&deg[dst[e]], 1);
}

// single-block exclusive scan over n ints (n ~ 50000)
__global__ __launch_bounds__(1024) void scan_kernel(const int* __restrict__ deg,
                                                    int* __restrict__ row_start, int n) {
    __shared__ int buf[1024];
    __shared__ int carry_s;
    int tid = threadIdx.x;
    if (tid == 0) carry_s = 0;
    __syncthreads();
    for (int base = 0; base < n; base += 1024) {
        int i = base + tid;
        int x = (i < n) ? deg[i] : 0;
        buf[tid] = x;
        __syncthreads();
        // inclusive Hillis-Steele scan
        for (int off = 1; off < 1024; off <<= 1) {
            int t = (tid >= off) ? buf[tid - off] : 0;
            __syncthreads();
            buf[tid] += t;
            __syncthreads();
        }
        int c = carry_s;
        if (i < n) row_start[i] = c + buf[tid] - x;  // exclusive
        __syncthreads();
        if (tid == 0) carry_s = c + buf[1023];
        __syncthreads();
    }
    if (tid == 0) row_start[n] = carry_s;
}

__global__ void copy_int_kernel(const int* __restrict__ a, int* __restrict__ b, int n) {
    int i = blockIdx.x * 256 + threadIdx.x;
    if (i < n) b[i] = a[i];
}

__global__ void fill_kernel(const int* __restrict__ src, const int* __restrict__ dst,
                            int* __restrict__ cursor, int* __restrict__ esrc, int E) {
    int e = blockIdx.x * 256 + threadIdx.x;
    if (e < E) {
        int d = dst[e];
        int pos = atomicAdd(&cursor[d], 1);
        esrc[pos] = src[e];
    }
}

// ---------------------------------------------------------------------------
// f32 tiled GEMM: C[M,N] = A[M,K] @ B[K,N]
// ---------------------------------------------------------------------------
#define BM 64
#define BN 64
#define BK 16

__global__ __launch_bounds__(256) void gemm_f32(const float* __restrict__ A,
                                                const float* __restrict__ B,
                                                float* __restrict__ C,
                                                int M, int K, int N) {
    __shared__ float As[BK][BM + 4];  // +4 pad: float4-aligned reads, 2-way-max conflicts
    __shared__ float Bs[BK][BN];
    int tid = threadIdx.x;
    int br = blockIdx.y * BM;
    int bc = blockIdx.x * BN;
    int tr = (tid >> 4) << 2;  // row offset within tile, 0..60
    int tc = (tid & 15) << 2;  // col offset within tile, 0..60

    float acc[4][4] = {};

    for (int k0 = 0; k0 < K; k0 += BK) {
        // A tile: BM x BK, k fastest for coalescing
        #pragma unroll
        for (int i = tid; i < BM * BK; i += 256) {
            int k = i & (BK - 1);
            int m = i >> 4;
            int gr = br + m, gk = k0 + k;
            As[k][m] = (gr < M && gk < K) ? A[(size_t)gr * K + gk] : 0.f;
        }
        // B tile: BK x BN, n fastest (fully coalesced)
        #pragma unroll
        for (int i = tid; i < BK * BN; i += 256) {
            int n = i & (BN - 1);
            int k = i >> 6;
            int gk = k0 + k, gc = bc + n;
            Bs[k][n] = (gk < K && gc < N) ? B[(size_t)gk * N + gc] : 0.f;
        }
        __syncthreads();
        #pragma unroll
        for (int k = 0; k < BK; ++k) {
            float a0 = As[k][tr + 0], a1 = As[k][tr + 1], a2 = As[k][tr + 2], a3 = As[k][tr + 3];
            float b0 = Bs[k][tc + 0], b1 = Bs[k][tc + 1], b2 = Bs[k][tc + 2], b3 = Bs[k][tc + 3];
            acc[0][0] += a0 * b0; acc[0][1] += a0 * b1; acc[0][2] += a0 * b2; acc[0][3] += a0 * b3;
            acc[1][0] += a1 * b0; acc[1][1] += a1 * b1; acc[1][2] += a1 * b2; acc[1][3] += a1 * b3;
            acc[2][0] += a2 * b0; acc[2][1] += a2 * b1; acc[2][2] += a2 * b2; acc[2][3] += a2 * b3;
            acc[3][0] += a3 * b0; acc[3][1] += a3 * b1; acc[3][2] += a3 * b2; acc[3][3] += a3 * b3;
        }
        __syncthreads();
    }

    #pragma unroll
    for (int r = 0; r < 4; ++r) {
        int gr = br + tr + r;
        if (gr < M) {
            #pragma unroll
            for (int c = 0; c < 4; ++c) {
                int gc = bc + tc + c;
                if (gc < N) C[(size_t)gr * N + gc] = acc[r][c];
            }
        }
    }
}

// ---------------------------------------------------------------------------
// Fused aggregation (CSR gather-sum) + bias + activation.
// One 64-lane wave per node; features across lanes (up to 4 per lane, F<=256).
// ACT: 0 = leaky_relu(0.01), 1 = softmax, 2 = log_softmax
// ---------------------------------------------------------------------------
template <int ACT>
__global__ __launch_bounds__(64) void agg_act_kernel(const float* __restrict__ H,
                                                     const int* __restrict__ row_start,
                                                     const int* __restrict__ esrc,
                                                     const float* __restrict__ bias,
                                                     float* __restrict__ Xout, int F) {
    int v = blockIdx.x;
    int lane = threadIdx.x;
    int e0 = row_start[v];
    int e1 = row_start[v + 1];

    float acc[4] = {0.f, 0.f, 0.f, 0.f};

    for (int e = e0; e < e1; ++e) {
        int s = esrc[e];  // broadcast load (same addr across lanes)
        const float* hr = H + (size_t)s * F;
        #pragma unroll
        for (int c = 0; c < 4; ++c) {
            int j = lane + (c << 6);
            if (j < F) acc[c] += hr[j];
        }
    }
    #pragma unroll
    for (int c = 0; c < 4; ++c) {
        int j = lane + (c << 6);
        if (j < F) acc[c] += bias[j];
    }

    float* orow = Xout + (size_t)v * F;

    if (ACT == 0) {
        #pragma unroll
        for (int c = 0; c < 4; ++c) {
            int j = lane + (c << 6);
            if (j < F) {
                float x = acc[c];
                orow[j] = (x >= 0.f) ? x : 0.01f * x;
            }
        }
    } else {
        // row max
        float m = -INFINITY;
        #pragma unroll
        for (int c = 0; c < 4; ++c) {
            int j = lane + (c << 6);
            if (j < F) m = fmaxf(m, acc[c]);
        }
        #pragma unroll
        for (int off = 32; off > 0; off >>= 1) m = fmaxf(m, __shfl_xor(m, off));
        // exp & sum
        float p[4];
        float s = 0.f;
        #pragma unroll
        for (int c = 0; c < 4; ++c) {
            int j = lane + (c << 6);
            if (j < F) {
                p[c] = expf(acc[c] - m);
                s += p[c];
            } else {
                p[c] = 0.f;
            }
        }
        #pragma unroll
        for (int off = 32; off > 0; off >>= 1) s += __shfl_xor(s, off);
        if (ACT == 1) {
            float inv = 1.f / s;
            #pragma unroll
            for (int c = 0; c < 4; ++c) {
                int j = lane + (c << 6);
                if (j < F) orow[j] = p[c] * inv;
            }
        } else {
            float ls = logf(s);
            #pragma unroll
            for (int c = 0; c < 4; ++c) {
                int j = lane + (c << 6);
                if (j < F) orow[j] = acc[c] - m - ls;
            }
        }
    }
}

// ---------------------------------------------------------------------------
// Host launch
// ---------------------------------------------------------------------------
static inline size_t align_up(size_t x, size_t a) { return (x + a - 1) & ~(a - 1); }

extern "C" void kernel_launch(void* const* d_in, const int* in_sizes, int n_in,
                              void* d_out, int out_size, void* d_ws, size_t ws_size,
                              hipStream_t stream) {
    const float* features = (const float*)d_in[0];
    const int* src = (const int*)d_in[1];
    const int* dst = (const int*)d_in[2];
    const float* W[6];
    const float* b[6];
    for (int l = 0; l < 6; ++l) {
        W[l] = (const float*)d_in[3 + 2 * l];
        b[l] = (const float*)d_in[4 + 2 * l];
    }

    const int fin[6]  = {300, 200, 150, 100, 50, 25};
    const int fout[6] = {200, 150, 100, 50, 25, 3};
    const int act[6]  = {0, 1, 0, 1, 0, 2};

    // workspace layout
    char* ws = (char*)d_ws;
    size_t off = 0;
    int* row_start = (int*)(ws + off); off = align_up(off + (N_NODES + 1) * sizeof(int), 256);
    int* cursor    = (int*)(ws + off); off = align_up(off + (N_NODES + 1) * sizeof(int), 256);
    int* esrc      = (int*)(ws + off); off = align_up(off + N_EDGES * sizeof(int), 256);
    float* B0      = (float*)(ws + off); off = align_up(off + (size_t)N_NODES * 200 * sizeof(float), 256);
    float* B1      = (float*)(ws + off); off = align_up(off + (size_t)N_NODES * 200 * sizeof(float), 256);
    (void)ws_size;

    // --- build CSR by dst (deg lives in `cursor` buffer temporarily) ---
    {
        int n1 = N_NODES + 1;
        zero_int_kernel<<<(n1 + 255) / 256, 256, 0, stream>>>(cursor, n1);
        count_kernel<<<(N_EDGES + 255) / 256, 256, 0, stream>>>(dst, cursor, N_EDGES);
        scan_kernel<<<1, 1024, 0, stream>>>(cursor, row_start, N_NODES);
        copy_int_kernel<<<(n1 + 255) / 256, 256, 0, stream>>>(row_start, cursor, n1);
        fill_kernel<<<(N_EDGES + 255) / 256, 256, 0, stream>>>(src, dst, cursor, esrc, N_EDGES);
    }

    // --- 6 layers: H = X@W (GEMM), then X' = act(agg(H) + b) ---
    const float* X = features;
    for (int l = 0; l < 6; ++l) {
        float* H = B0;
        dim3 ggrid((fout[l] + BN - 1) / BN, (N_NODES + BM - 1) / BM);
        gemm_f32<<<ggrid, 256, 0, stream>>>(X, W[l], H, N_NODES, fin[l], fout[l]);

        float* out = (l == 5) ? (float*)d_out : B1;
        if (act[l] == 0)
            agg_act_kernel<0><<<N_NODES, 64, 0, stream>>>(H, row_start, esrc, b[l], out, fout[l]);
        else if (act[l] == 1)
            agg_act_kernel<1><<<N_NODES, 64, 0, stream>>>(H, row_start, esrc, b[l], out, fout[l]);
        else
            agg_act_kernel<2><<<N_NODES, 64, 0, stream>>>(H, row_start, esrc, b[l], out, fout[l]);
        X = out;
    }
    (void)out_size; (void)n_in; (void)in_sizes;
}

// Round 2
// 557.027 us; speedup vs baseline: 1.3933x; 1.3933x over previous
//
#include <hip/hip_runtime.h>
#include <math.h>

#define N_NODES 50000
#define N_EDGES 262144

using short8 = __attribute__((ext_vector_type(8))) short;
using f32x4  = __attribute__((ext_vector_type(4))) float;

// ---------------------------------------------------------------------------
// bf16 split helpers (RNE)
// ---------------------------------------------------------------------------
__device__ __forceinline__ ushort bf16_rne(float x) {
    uint u = __float_as_uint(x);
    uint r = (u + 0x7FFFu + ((u >> 16) & 1u)) >> 16;
    return (ushort)r;
}
__device__ __forceinline__ float bf16_to_f32(ushort h) {
    return __uint_as_float(((uint)h) << 16);
}

// ---------------------------------------------------------------------------
// CSR build kernels
// ---------------------------------------------------------------------------
__global__ void zero_int_kernel(int* p, int n) {
    int i = blockIdx.x * 256 + threadIdx.x;
    if (i < n) p[i] = 0;
}

__global__ void count_kernel(const int* __restrict__ dst, int* __restrict__ deg, int E) {
    int e = blockIdx.x * 256 + threadIdx.x;
    if (e < E) atomicAdd(&deg[dst[e]], 1);
}

__global__ __launch_bounds__(1024) void scan_kernel(const int* __restrict__ deg,
                                                    int* __restrict__ row_start, int n) {
    __shared__ int buf[1024];
    __shared__ int carry_s;
    int tid = threadIdx.x;
    if (tid == 0) carry_s = 0;
    __syncthreads();
    for (int base = 0; base < n; base += 1024) {
        int i = base + tid;
        int x = (i < n) ? deg[i] : 0;
        buf[tid] = x;
        __syncthreads();
        for (int off = 1; off < 1024; off <<= 1) {
            int t = (tid >= off) ? buf[tid - off] : 0;
            __syncthreads();
            buf[tid] += t;
            __syncthreads();
        }
        int c = carry_s;
        if (i < n) row_start[i] = c + buf[tid] - x;
        __syncthreads();
        if (tid == 0) carry_s = c + buf[1023];
        __syncthreads();
    }
    if (tid == 0) row_start[n] = carry_s;
}

__global__ void copy_int_kernel(const int* __restrict__ a, int* __restrict__ b, int n) {
    int i = blockIdx.x * 256 + threadIdx.x;
    if (i < n) b[i] = a[i];
}

__global__ void fill_kernel(const int* __restrict__ src, const int* __restrict__ dst,
                            int* __restrict__ cursor, int* __restrict__ esrc, int E) {
    int e = blockIdx.x * 256 + threadIdx.x;
    if (e < E) {
        int d = dst[e];
        int pos = atomicAdd(&cursor[d], 1);
        esrc[pos] = src[e];
    }
}

// ---------------------------------------------------------------------------
// f32 -> (hi,lo) bf16 conversion, padded K (features only; later layers fused)
// ---------------------------------------------------------------------------
template <int F, int KP>
__global__ void convert_x(const float* __restrict__ X, ushort* __restrict__ hi,
                          ushort* __restrict__ lo, int M) {
    int idx = blockIdx.x * 256 + threadIdx.x;
    int row = idx / KP;
    int col = idx - row * KP;
    if (row >= M) return;
    float v = (col < F) ? X[(size_t)row * F + col] : 0.f;
    ushort h = bf16_rne(v);
    hi[idx] = h;
    lo[idx] = bf16_rne(v - bf16_to_f32(h));
}

// W [K][N] f32 -> Wt hi/lo [NP][KP] bf16 (transposed, zero-padded), all layers fused
struct WtDesc { const float* W; ushort* hi; ushort* lo; int K, N, KP, NP; };
struct WtDescs { WtDesc d[6]; };

__global__ void convert_w(WtDescs all) {
    WtDesc d = all.d[blockIdx.y];
    int total = d.NP * d.KP;
    for (int idx = blockIdx.x * 256 + threadIdx.x; idx < total; idx += gridDim.x * 256) {
        int n = idx / d.KP;
        int k = idx - n * d.KP;
        float v = (n < d.N && k < d.K) ? d.W[(size_t)k * d.N + n] : 0.f;
        ushort h = bf16_rne(v);
        d.hi[idx] = h;
        d.lo[idx] = bf16_rne(v - bf16_to_f32(h));
    }
}

// ---------------------------------------------------------------------------
// Split-bf16 MFMA GEMM: C[M,N] = A[M,KP] @ B^T[NP,KP]  (3-term split, f32 acc)
// Block 256 thr = 4 waves, tile BM=128 x BN=64, each wave 32x64. K-step 32.
// ---------------------------------------------------------------------------
template <int KP>
__global__ __launch_bounds__(256) void gemm_split(const ushort* __restrict__ Ahi,
                                                  const ushort* __restrict__ Alo,
                                                  const ushort* __restrict__ Bhi,
                                                  const ushort* __restrict__ Blo,
                                                  float* __restrict__ C, int M, int N) {
    // +8 ushort (16B) row pad -> 80B stride: b128 reads are 2-way-max bank alias (free)
    __shared__ __align__(16) ushort AsH[128][40];
    __shared__ __align__(16) ushort AsL[128][40];
    __shared__ __align__(16) ushort BsH[64][40];
    __shared__ __align__(16) ushort BsL[64][40];

    const int tid = threadIdx.x;
    const int lane = tid & 63;
    const int w = tid >> 6;
    const int brow = blockIdx.y * 128;
    const int bcol = blockIdx.x * 64;

    f32x4 acc[2][4];
    #pragma unroll
    for (int mt = 0; mt < 2; ++mt)
        #pragma unroll
        for (int nt = 0; nt < 4; ++nt)
            acc[mt][nt] = (f32x4){0.f, 0.f, 0.f, 0.f};

    // staging maps
    const int ar = tid >> 1;        // 0..127 (A row)
    const int aq = (tid & 1) * 2;   // quarters {0,1} or {2,3}
    const int br_ = tid >> 2;       // 0..63 (B row)
    const int bq = tid & 3;         // quarter
    const bool arow_ok = (brow + ar) < M;
    const size_t arow_off = (size_t)(brow + ar) * KP;
    const size_t brow_off = (size_t)(bcol + br_) * KP;

    const short8 zz = {0, 0, 0, 0, 0, 0, 0, 0};

    for (int kt = 0; kt < KP / 32; ++kt) {
        const int k0 = kt * 32;
        #pragma unroll
        for (int qq = 0; qq < 2; ++qq) {
            int q = aq + qq;
            short8 vh = arow_ok ? *(const short8*)(const void*)(Ahi + arow_off + k0 + q * 8) : zz;
            short8 vl = arow_ok ? *(const short8*)(const void*)(Alo + arow_off + k0 + q * 8) : zz;
            *(short8*)(void*)&AsH[ar][q * 8] = vh;
            *(short8*)(void*)&AsL[ar][q * 8] = vl;
        }
        *(short8*)(void*)&BsH[br_][bq * 8] = *(const short8*)(const void*)(Bhi + brow_off + k0 + bq * 8);
        *(short8*)(void*)&BsL[br_][bq * 8] = *(const short8*)(const void*)(Blo + brow_off + k0 + bq * 8);
        __syncthreads();

        const int fr = lane & 15;
        const int fk = (lane >> 4) * 8;
        short8 ah[2], al[2], bh[4], bl[4];
        #pragma unroll
        for (int mt = 0; mt < 2; ++mt) {
            int r = w * 32 + mt * 16 + fr;
            ah[mt] = *(const short8*)(const void*)&AsH[r][fk];
            al[mt] = *(const short8*)(const void*)&AsL[r][fk];
        }
        #pragma unroll
        for (int nt = 0; nt < 4; ++nt) {
            int r = nt * 16 + fr;
            bh[nt] = *(const short8*)(const void*)&BsH[r][fk];
            bl[nt] = *(const short8*)(const void*)&BsL[r][fk];
        }
        #pragma unroll
        for (int mt = 0; mt < 2; ++mt)
            #pragma unroll
            for (int nt = 0; nt < 4; ++nt) {
                acc[mt][nt] = __builtin_amdgcn_mfma_f32_16x16x32_bf16(ah[mt], bh[nt], acc[mt][nt], 0, 0, 0);
                acc[mt][nt] = __builtin_amdgcn_mfma_f32_16x16x32_bf16(ah[mt], bl[nt], acc[mt][nt], 0, 0, 0);
                acc[mt][nt] = __builtin_amdgcn_mfma_f32_16x16x32_bf16(al[mt], bh[nt], acc[mt][nt], 0, 0, 0);
            }
        __syncthreads();
    }

    // epilogue: D layout col=lane&15, row=(lane>>4)*4+reg (m89-verified)
    const int fr = lane & 15;
    const int fq = lane >> 4;
    #pragma unroll
    for (int mt = 0; mt < 2; ++mt)
        #pragma unroll
        for (int nt = 0; nt < 4; ++nt)
            #pragma unroll
            for (int r = 0; r < 4; ++r) {
                int row = brow + w * 32 + mt * 16 + fq * 4 + r;
                int col = bcol + nt * 16 + fr;
                if (row < M && col < N) C[(size_t)row * N + col] = acc[mt][nt][r];
            }
}

// ---------------------------------------------------------------------------
// Fused aggregation + bias + activation.
// ACT: 0 = leaky_relu, 1 = softmax, 2 = log_softmax
// KPOUT == 0: write f32 [v*F+j]. KPOUT > 0: write split-bf16 padded [v*KPOUT+j].
// ---------------------------------------------------------------------------
template <int ACT, int KPOUT>
__global__ __launch_bounds__(64) void agg_act(const float* __restrict__ H,
                                              const int* __restrict__ row_start,
                                              const int* __restrict__ esrc,
                                              const float* __restrict__ bias,
                                              float* __restrict__ outF,
                                              ushort* __restrict__ ohi,
                                              ushort* __restrict__ olo, int F) {
    int v = blockIdx.x;
    int lane = threadIdx.x;
    int e0 = row_start[v];
    int e1 = row_start[v + 1];

    float acc[4] = {0.f, 0.f, 0.f, 0.f};
    for (int e = e0; e < e1; ++e) {
        int s = esrc[e];
        const float* hr = H + (size_t)s * F;
        #pragma unroll
        for (int c = 0; c < 4; ++c) {
            int j = lane + (c << 6);
            if (j < F) acc[c] += hr[j];
        }
    }
    #pragma unroll
    for (int c = 0; c < 4; ++c) {
        int j = lane + (c << 6);
        if (j < F) acc[c] += bias[j];
    }

    float res[4] = {0.f, 0.f, 0.f, 0.f};
    if (ACT == 0) {
        #pragma unroll
        for (int c = 0; c < 4; ++c) {
            float x = acc[c];
            res[c] = (x >= 0.f) ? x : 0.01f * x;
        }
    } else {
        float m = -INFINITY;
        #pragma unroll
        for (int c = 0; c < 4; ++c) {
            int j = lane + (c << 6);
            if (j < F) m = fmaxf(m, acc[c]);
        }
        #pragma unroll
        for (int off = 32; off > 0; off >>= 1) m = fmaxf(m, __shfl_xor(m, off));
        float p[4];
        float s = 0.f;
        #pragma unroll
        for (int c = 0; c < 4; ++c) {
            int j = lane + (c << 6);
            if (j < F) { p[c] = expf(acc[c] - m); s += p[c]; } else p[c] = 0.f;
        }
        #pragma unroll
        for (int off = 32; off > 0; off >>= 1) s += __shfl_xor(s, off);
        if (ACT == 1) {
            float inv = 1.f / s;
            #pragma unroll
            for (int c = 0; c < 4; ++c) res[c] = p[c] * inv;
        } else {
            float ls = logf(s);
            #pragma unroll
            for (int c = 0; c < 4; ++c) res[c] = acc[c] - m - ls;
        }
    }

    if (KPOUT == 0) {
        float* orow = outF + (size_t)v * F;
        #pragma unroll
        for (int c = 0; c < 4; ++c) {
            int j = lane + (c << 6);
            if (j < F) orow[j] = res[c];
        }
    } else {
        size_t base = (size_t)v * KPOUT;
        #pragma unroll
        for (int c = 0; c < 4; ++c) {
            int j = lane + (c << 6);
            if (j < KPOUT) {
                float y = (j < F) ? res[c] : 0.f;
                ushort h = bf16_rne(y);
                ohi[base + j] = h;
                olo[base + j] = bf16_rne(y - bf16_to_f32(h));
            }
        }
    }
}

// ---------------------------------------------------------------------------
// Host launch
// ---------------------------------------------------------------------------
static inline size_t align_up(size_t x, size_t a) { return (x + a - 1) & ~(a - 1); }

extern "C" void kernel_launch(void* const* d_in, const int* in_sizes, int n_in,
                              void* d_out, int out_size, void* d_ws, size_t ws_size,
                              hipStream_t stream) {
    const float* features = (const float*)d_in[0];
    const int* src = (const int*)d_in[1];
    const int* dst = (const int*)d_in[2];
    const float* W[6];
    const float* b[6];
    for (int l = 0; l < 6; ++l) {
        W[l] = (const float*)d_in[3 + 2 * l];
        b[l] = (const float*)d_in[4 + 2 * l];
    }

    // per-layer geometry
    const int fout[6] = {200, 150, 100, 50, 25, 3};
    const int KPin[6] = {320, 224, 160, 128, 64, 32};   // padded K of GEMM l
    const int NPl[6]  = {256, 192, 128, 64, 64, 64};    // padded N (Wt rows)

    // workspace layout
    char* ws = (char*)d_ws;
    size_t off = 0;
    int* row_start = (int*)(ws + off); off = align_up(off + (N_NODES + 1) * sizeof(int), 256);
    int* cursor    = (int*)(ws + off); off = align_up(off + (N_NODES + 1) * sizeof(int), 256);
    int* esrc      = (int*)(ws + off); off = align_up(off + N_EDGES * sizeof(int), 256);
    ushort* Wthi[6];
    ushort* Wtlo[6];
    for (int l = 0; l < 6; ++l) {
        Wthi[l] = (ushort*)(ws + off); off = align_up(off + (size_t)NPl[l] * KPin[l] * 2, 256);
        Wtlo[l] = (ushort*)(ws + off); off = align_up(off + (size_t)NPl[l] * KPin[l] * 2, 256);
    }
    ushort* Xhi = (ushort*)(ws + off); off = align_up(off + (size_t)N_NODES * 320 * 2, 256);
    ushort* Xlo = (ushort*)(ws + off); off = align_up(off + (size_t)N_NODES * 320 * 2, 256);
    float* H    = (float*)(ws + off);  off = align_up(off + (size_t)N_NODES * 200 * 4, 256);
    (void)ws_size;

    // --- build CSR by dst ---
    {
        int n1 = N_NODES + 1;
        zero_int_kernel<<<(n1 + 255) / 256, 256, 0, stream>>>(cursor, n1);
        count_kernel<<<(N_EDGES + 255) / 256, 256, 0, stream>>>(dst, cursor, N_EDGES);
        scan_kernel<<<1, 1024, 0, stream>>>(cursor, row_start, N_NODES);
        copy_int_kernel<<<(n1 + 255) / 256, 256, 0, stream>>>(row_start, cursor, n1);
        fill_kernel<<<(N_EDGES + 255) / 256, 256, 0, stream>>>(src, dst, cursor, esrc, N_EDGES);
    }

    // --- weight conversion (all 6 layers, one launch) ---
    {
        WtDescs wd;
        const int fin[6] = {300, 200, 150, 100, 50, 25};
        for (int l = 0; l < 6; ++l)
            wd.d[l] = WtDesc{W[l], Wthi[l], Wtlo[l], fin[l], fout[l], KPin[l], NPl[l]};
        convert_w<<<dim3(320, 6), 256, 0, stream>>>(wd);
    }

    // --- features -> split bf16 padded ---
    {
        int total = N_NODES * 320;
        convert_x<300, 320><<<(total + 255) / 256, 256, 0, stream>>>(features, Xhi, Xlo, N_NODES);
    }

    const int gy = (N_NODES + 127) / 128;

    // layer 1: GEMM K=320, then agg+leaky -> split bf16 KP=224
    gemm_split<320><<<dim3(NPl[0] / 64, gy), 256, 0, stream>>>(Xhi, Xlo, Wthi[0], Wtlo[0], H, N_NODES, fout[0]);
    agg_act<0, 224><<<N_NODES, 64, 0, stream>>>(H, row_start, esrc, b[0], nullptr, Xhi, Xlo, fout[0]);

    // layer 2: softmax -> KP=160
    gemm_split<224><<<dim3(NPl[1] / 64, gy), 256, 0, stream>>>(Xhi, Xlo, Wthi[1], Wtlo[1], H, N_NODES, fout[1]);
    agg_act<1, 160><<<N_NODES, 64, 0, stream>>>(H, row_start, esrc, b[1], nullptr, Xhi, Xlo, fout[1]);

    // layer 3: leaky -> KP=128
    gemm_split<160><<<dim3(NPl[2] / 64, gy), 256, 0, stream>>>(Xhi, Xlo, Wthi[2], Wtlo[2], H, N_NODES, fout[2]);
    agg_act<0, 128><<<N_NODES, 64, 0, stream>>>(H, row_start, esrc, b[2], nullptr, Xhi, Xlo, fout[2]);

    // layer 4: softmax -> KP=64
    gemm_split<128><<<dim3(NPl[3] / 64, gy), 256, 0, stream>>>(Xhi, Xlo, Wthi[3], Wtlo[3], H, N_NODES, fout[3]);
    agg_act<1, 64><<<N_NODES, 64, 0, stream>>>(H, row_start, esrc, b[3], nullptr, Xhi, Xlo, fout[3]);

    // layer 5: leaky -> KP=32
    gemm_split<64><<<dim3(NPl[4] / 64, gy), 256, 0, stream>>>(Xhi, Xlo, Wthi[4], Wtlo[4], H, N_NODES, fout[4]);
    agg_act<0, 32><<<N_NODES, 64, 0, stream>>>(H, row_start, esrc, b[4], nullptr, Xhi, Xlo, fout[4]);

    // layer 6: log_softmax -> f32 d_out
    gemm_split<32><<<dim3(NPl[5] / 64, gy), 256, 0, stream>>>(Xhi, Xlo, Wthi[5], Wtlo[5], H, N_NODES, fout[5]);
    agg_act<2, 0><<<N_NODES, 64, 0, stream>>>(H, row_start, esrc, b[5], (float*)d_out, nullptr, nullptr, fout[5]);

    (void)out_size; (void)n_in; (void)in_sizes;
}

// Round 3
// 473.939 us; speedup vs baseline: 1.6376x; 1.1753x over previous
//
#include <hip/hip_runtime.h>
#include <math.h>

#define N_NODES 50000
#define N_EDGES 262144

using short8 = __attribute__((ext_vector_type(8))) short;
using f32x4  = __attribute__((ext_vector_type(4))) float;

// ---------------------------------------------------------------------------
// bf16 split helpers (RNE)
// ---------------------------------------------------------------------------
__device__ __forceinline__ ushort bf16_rne(float x) {
    uint u = __float_as_uint(x);
    uint r = (u + 0x7FFFu + ((u >> 16) & 1u)) >> 16;
    return (ushort)r;
}
__device__ __forceinline__ float bf16_to_f32(ushort h) {
    return __uint_as_float(((uint)h) << 16);
}

// ---------------------------------------------------------------------------
// CSR build kernels
// ---------------------------------------------------------------------------
__global__ void zero_int_kernel(int* p, int n) {
    int i = blockIdx.x * 256 + threadIdx.x;
    if (i < n) p[i] = 0;
}

__global__ void count_kernel(const int* __restrict__ dst, int* __restrict__ deg, int E) {
    int e = blockIdx.x * 256 + threadIdx.x;
    if (e < E) atomicAdd(&deg[dst[e]], 1);
}

// --- 3-phase scan: 50000 ints, 49 blocks x 1024 elems ---
// phase 1: per-block local exclusive scan + block sum
__global__ __launch_bounds__(256) void scan_p1(const int* __restrict__ deg,
                                               int* __restrict__ local,
                                               int* __restrict__ blockSums, int n) {
    __shared__ int wsum[4];
    int b = blockIdx.x;
    int t = threadIdx.x;
    int i0 = b * 1024 + t * 4;
    int x0 = 0, x1 = 0, x2 = 0, x3 = 0;
    if (i0 + 3 < n) {
        int4 v = *(const int4*)(const void*)(deg + i0);
        x0 = v.x; x1 = v.y; x2 = v.z; x3 = v.w;
    } else {
        if (i0 + 0 < n) x0 = deg[i0 + 0];
        if (i0 + 1 < n) x1 = deg[i0 + 1];
        if (i0 + 2 < n) x2 = deg[i0 + 2];
        if (i0 + 3 < n) x3 = deg[i0 + 3];
    }
    int s = x0 + x1 + x2 + x3;
    int lane = t & 63;
    int wid = t >> 6;
    int incl = s;
    #pragma unroll
    for (int off = 1; off < 64; off <<= 1) {
        int u = __shfl_up(incl, off);
        if (lane >= off) incl += u;
    }
    if (lane == 63) wsum[wid] = incl;
    __syncthreads();
    int woff = 0;
    #pragma unroll
    for (int k = 0; k < 4; ++k)
        if (k < wid) woff += wsum[k];
    int texcl = woff + incl - s;  // exclusive prefix of this thread's 4-group
    if (i0 + 3 < n) {
        int4 o;
        o.x = texcl;
        o.y = texcl + x0;
        o.z = texcl + x0 + x1;
        o.w = texcl + x0 + x1 + x2;
        *(int4*)(void*)(local + i0) = o;
    } else {
        if (i0 + 0 < n) local[i0 + 0] = texcl;
        if (i0 + 1 < n) local[i0 + 1] = texcl + x0;
        if (i0 + 2 < n) local[i0 + 2] = texcl + x0 + x1;
        if (i0 + 3 < n) local[i0 + 3] = texcl + x0 + x1 + x2;
    }
    if (t == 0) blockSums[b] = wsum[0] + wsum[1] + wsum[2] + wsum[3];
}

// phase 2: single wave scans block sums (nb <= 64)
__global__ __launch_bounds__(64) void scan_p2(int* __restrict__ blockSums, int nb) {
    int lane = threadIdx.x;
    int s = (lane < nb) ? blockSums[lane] : 0;
    int incl = s;
    #pragma unroll
    for (int off = 1; off < 64; off <<= 1) {
        int u = __shfl_up(incl, off);
        if (lane >= off) incl += u;
    }
    if (lane < nb) blockSums[lane] = incl - s;  // exclusive
}

// phase 3: add block offsets; write row_start AND cursor copy
__global__ __launch_bounds__(256) void scan_p3(const int* __restrict__ local,
                                               const int* __restrict__ blockSums,
                                               int* __restrict__ row_start,
                                               int* __restrict__ cursor, int n, int total) {
    int b = blockIdx.x;
    int off = blockSums[b];
    int i0 = b * 1024 + threadIdx.x * 4;
    if (i0 + 3 < n) {
        int4 v = *(const int4*)(const void*)(local + i0);
        v.x += off; v.y += off; v.z += off; v.w += off;
        *(int4*)(void*)(row_start + i0) = v;
        *(int4*)(void*)(cursor + i0) = v;
    } else {
        #pragma unroll
        for (int k = 0; k < 4; ++k)
            if (i0 + k < n) {
                int v = local[i0 + k] + off;
                row_start[i0 + k] = v;
                cursor[i0 + k] = v;
            }
    }
    if (b == 0 && threadIdx.x == 0) row_start[n] = total;
}

__global__ void fill_kernel(const int* __restrict__ src, const int* __restrict__ dst,
                            int* __restrict__ cursor, int* __restrict__ esrc, int E) {
    int e = blockIdx.x * 256 + threadIdx.x;
    if (e < E) {
        int d = dst[e];
        int pos = atomicAdd(&cursor[d], 1);
        esrc[pos] = src[e];
    }
}

// ---------------------------------------------------------------------------
// f32 -> (hi,lo) bf16 conversion, padded K (features only; later layers fused)
// ---------------------------------------------------------------------------
template <int F, int KP>
__global__ void convert_x(const float* __restrict__ X, ushort* __restrict__ hi,
                          ushort* __restrict__ lo, int M) {
    int idx = blockIdx.x * 256 + threadIdx.x;
    int row = idx / KP;
    int col = idx - row * KP;
    if (row >= M) return;
    float v = (col < F) ? X[(size_t)row * F + col] : 0.f;
    ushort h = bf16_rne(v);
    hi[idx] = h;
    lo[idx] = bf16_rne(v - bf16_to_f32(h));
}

// W [K][N] f32 -> Wt hi/lo [NP][KP] bf16 (transposed, zero-padded), all layers fused
struct WtDesc { const float* W; ushort* hi; ushort* lo; int K, N, KP, NP; };
struct WtDescs { WtDesc d[6]; };

__global__ void convert_w(WtDescs all) {
    WtDesc d = all.d[blockIdx.y];
    int total = d.NP * d.KP;
    for (int idx = blockIdx.x * 256 + threadIdx.x; idx < total; idx += gridDim.x * 256) {
        int n = idx / d.KP;
        int k = idx - n * d.KP;
        float v = (n < d.N && k < d.K) ? d.W[(size_t)k * d.N + n] : 0.f;
        ushort h = bf16_rne(v);
        d.hi[idx] = h;
        d.lo[idx] = bf16_rne(v - bf16_to_f32(h));
    }
}

// ---------------------------------------------------------------------------
// Split-bf16 MFMA GEMM: C[M,N] = A[M,KP] @ B^T[NP,KP]  (3-term split, f32 acc)
// Block 256 thr = 4 waves, tile BM=128 x BN=64, each wave 32x64. K-step 32.
// ---------------------------------------------------------------------------
template <int KP>
__global__ __launch_bounds__(256) void gemm_split(const ushort* __restrict__ Ahi,
                                                  const ushort* __restrict__ Alo,
                                                  const ushort* __restrict__ Bhi,
                                                  const ushort* __restrict__ Blo,
                                                  float* __restrict__ C, int M, int N) {
    __shared__ __align__(16) ushort AsH[128][40];
    __shared__ __align__(16) ushort AsL[128][40];
    __shared__ __align__(16) ushort BsH[64][40];
    __shared__ __align__(16) ushort BsL[64][40];

    const int tid = threadIdx.x;
    const int lane = tid & 63;
    const int w = tid >> 6;
    const int brow = blockIdx.y * 128;
    const int bcol = blockIdx.x * 64;

    f32x4 acc[2][4];
    #pragma unroll
    for (int mt = 0; mt < 2; ++mt)
        #pragma unroll
        for (int nt = 0; nt < 4; ++nt)
            acc[mt][nt] = (f32x4){0.f, 0.f, 0.f, 0.f};

    const int ar = tid >> 1;
    const int aq = (tid & 1) * 2;
    const int br_ = tid >> 2;
    const int bq = tid & 3;
    const bool arow_ok = (brow + ar) < M;
    const size_t arow_off = (size_t)(brow + ar) * KP;
    const size_t brow_off = (size_t)(bcol + br_) * KP;

    const short8 zz = {0, 0, 0, 0, 0, 0, 0, 0};

    for (int kt = 0; kt < KP / 32; ++kt) {
        const int k0 = kt * 32;
        #pragma unroll
        for (int qq = 0; qq < 2; ++qq) {
            int q = aq + qq;
            short8 vh = arow_ok ? *(const short8*)(const void*)(Ahi + arow_off + k0 + q * 8) : zz;
            short8 vl = arow_ok ? *(const short8*)(const void*)(Alo + arow_off + k0 + q * 8) : zz;
            *(short8*)(void*)&AsH[ar][q * 8] = vh;
            *(short8*)(void*)&AsL[ar][q * 8] = vl;
        }
        *(short8*)(void*)&BsH[br_][bq * 8] = *(const short8*)(const void*)(Bhi + brow_off + k0 + bq * 8);
        *(short8*)(void*)&BsL[br_][bq * 8] = *(const short8*)(const void*)(Blo + brow_off + k0 + bq * 8);
        __syncthreads();

        const int fr = lane & 15;
        const int fk = (lane >> 4) * 8;
        short8 ah[2], al[2], bh[4], bl[4];
        #pragma unroll
        for (int mt = 0; mt < 2; ++mt) {
            int r = w * 32 + mt * 16 + fr;
            ah[mt] = *(const short8*)(const void*)&AsH[r][fk];
            al[mt] = *(const short8*)(const void*)&AsL[r][fk];
        }
        #pragma unroll
        for (int nt = 0; nt < 4; ++nt) {
            int r = nt * 16 + fr;
            bh[nt] = *(const short8*)(const void*)&BsH[r][fk];
            bl[nt] = *(const short8*)(const void*)&BsL[r][fk];
        }
        #pragma unroll
        for (int mt = 0; mt < 2; ++mt)
            #pragma unroll
            for (int nt = 0; nt < 4; ++nt) {
                acc[mt][nt] = __builtin_amdgcn_mfma_f32_16x16x32_bf16(ah[mt], bh[nt], acc[mt][nt], 0, 0, 0);
                acc[mt][nt] = __builtin_amdgcn_mfma_f32_16x16x32_bf16(ah[mt], bl[nt], acc[mt][nt], 0, 0, 0);
                acc[mt][nt] = __builtin_amdgcn_mfma_f32_16x16x32_bf16(al[mt], bh[nt], acc[mt][nt], 0, 0, 0);
            }
        __syncthreads();
    }

    const int fr = lane & 15;
    const int fq = lane >> 4;
    #pragma unroll
    for (int mt = 0; mt < 2; ++mt)
        #pragma unroll
        for (int nt = 0; nt < 4; ++nt)
            #pragma unroll
            for (int r = 0; r < 4; ++r) {
                int row = brow + w * 32 + mt * 16 + fq * 4 + r;
                int col = bcol + nt * 16 + fr;
                if (row < M && col < N) C[(size_t)row * N + col] = acc[mt][nt][r];
            }
}

// ---------------------------------------------------------------------------
// Fused aggregation + bias + activation.
// ACT: 0 = leaky_relu, 1 = softmax, 2 = log_softmax
// KPOUT == 0: write f32 [v*F+j]. KPOUT > 0: write split-bf16 padded [v*KPOUT+j].
// ---------------------------------------------------------------------------
template <int ACT, int KPOUT>
__global__ __launch_bounds__(64) void agg_act(const float* __restrict__ H,
                                              const int* __restrict__ row_start,
                                              const int* __restrict__ esrc,
                                              const float* __restrict__ bias,
                                              float* __restrict__ outF,
                                              ushort* __restrict__ ohi,
                                              ushort* __restrict__ olo, int F) {
    int v = blockIdx.x;
    int lane = threadIdx.x;
    int e0 = row_start[v];
    int e1 = row_start[v + 1];

    float acc[4] = {0.f, 0.f, 0.f, 0.f};
    for (int e = e0; e < e1; ++e) {
        int s = esrc[e];
        const float* hr = H + (size_t)s * F;
        #pragma unroll
        for (int c = 0; c < 4; ++c) {
            int j = lane + (c << 6);
            if (j < F) acc[c] += hr[j];
        }
    }
    #pragma unroll
    for (int c = 0; c < 4; ++c) {
        int j = lane + (c << 6);
        if (j < F) acc[c] += bias[j];
    }

    float res[4] = {0.f, 0.f, 0.f, 0.f};
    if (ACT == 0) {
        #pragma unroll
        for (int c = 0; c < 4; ++c) {
            float x = acc[c];
            res[c] = (x >= 0.f) ? x : 0.01f * x;
        }
    } else {
        float m = -INFINITY;
        #pragma unroll
        for (int c = 0; c < 4; ++c) {
            int j = lane + (c << 6);
            if (j < F) m = fmaxf(m, acc[c]);
        }
        #pragma unroll
        for (int off = 32; off > 0; off >>= 1) m = fmaxf(m, __shfl_xor(m, off));
        float p[4];
        float s = 0.f;
        #pragma unroll
        for (int c = 0; c < 4; ++c) {
            int j = lane + (c << 6);
            if (j < F) { p[c] = expf(acc[c] - m); s += p[c]; } else p[c] = 0.f;
        }
        #pragma unroll
        for (int off = 32; off > 0; off >>= 1) s += __shfl_xor(s, off);
        if (ACT == 1) {
            float inv = 1.f / s;
            #pragma unroll
            for (int c = 0; c < 4; ++c) res[c] = p[c] * inv;
        } else {
            float ls = logf(s);
            #pragma unroll
            for (int c = 0; c < 4; ++c) res[c] = acc[c] - m - ls;
        }
    }

    if (KPOUT == 0) {
        float* orow = outF + (size_t)v * F;
        #pragma unroll
        for (int c = 0; c < 4; ++c) {
            int j = lane + (c << 6);
            if (j < F) orow[j] = res[c];
        }
    } else {
        size_t base = (size_t)v * KPOUT;
        #pragma unroll
        for (int c = 0; c < 4; ++c) {
            int j = lane + (c << 6);
            if (j < KPOUT) {
                float y = (j < F) ? res[c] : 0.f;
                ushort h = bf16_rne(y);
                ohi[base + j] = h;
                olo[base + j] = bf16_rne(y - bf16_to_f32(h));
            }
        }
    }
}

// ---------------------------------------------------------------------------
// Host launch
// ---------------------------------------------------------------------------
static inline size_t align_up(size_t x, size_t a) { return (x + a - 1) & ~(a - 1); }

extern "C" void kernel_launch(void* const* d_in, const int* in_sizes, int n_in,
                              void* d_out, int out_size, void* d_ws, size_t ws_size,
                              hipStream_t stream) {
    const float* features = (const float*)d_in[0];
    const int* src = (const int*)d_in[1];
    const int* dst = (const int*)d_in[2];
    const float* W[6];
    const float* b[6];
    for (int l = 0; l < 6; ++l) {
        W[l] = (const float*)d_in[3 + 2 * l];
        b[l] = (const float*)d_in[4 + 2 * l];
    }

    const int fout[6] = {200, 150, 100, 50, 25, 3};
    const int KPin[6] = {320, 224, 160, 128, 64, 32};
    const int NPl[6]  = {256, 192, 128, 64, 64, 64};

    // workspace layout
    char* ws = (char*)d_ws;
    size_t off = 0;
    int* row_start = (int*)(ws + off); off = align_up(off + (N_NODES + 1) * sizeof(int), 256);
    int* cursor    = (int*)(ws + off); off = align_up(off + (N_NODES + 1) * sizeof(int), 256);
    int* esrc      = (int*)(ws + off); off = align_up(off + N_EDGES * sizeof(int), 256);
    int* scan_loc  = (int*)(ws + off); off = align_up(off + N_NODES * sizeof(int), 256);
    int* blockSums = (int*)(ws + off); off = align_up(off + 64 * sizeof(int), 256);
    ushort* Wthi[6];
    ushort* Wtlo[6];
    for (int l = 0; l < 6; ++l) {
        Wthi[l] = (ushort*)(ws + off); off = align_up(off + (size_t)NPl[l] * KPin[l] * 2, 256);
        Wtlo[l] = (ushort*)(ws + off); off = align_up(off + (size_t)NPl[l] * KPin[l] * 2, 256);
    }
    ushort* Xhi = (ushort*)(ws + off); off = align_up(off + (size_t)N_NODES * 320 * 2, 256);
    ushort* Xlo = (ushort*)(ws + off); off = align_up(off + (size_t)N_NODES * 320 * 2, 256);
    float* H    = (float*)(ws + off);  off = align_up(off + (size_t)N_NODES * 200 * 4, 256);
    (void)ws_size;

    // --- build CSR by dst ---
    {
        const int nb = (N_NODES + 1023) / 1024;  // 49
        zero_int_kernel<<<(N_NODES + 255) / 256, 256, 0, stream>>>(cursor, N_NODES);
        count_kernel<<<(N_EDGES + 255) / 256, 256, 0, stream>>>(dst, cursor, N_EDGES);
        scan_p1<<<nb, 256, 0, stream>>>(cursor, scan_loc, blockSums, N_NODES);
        scan_p2<<<1, 64, 0, stream>>>(blockSums, nb);
        scan_p3<<<nb, 256, 0, stream>>>(scan_loc, blockSums, row_start, cursor, N_NODES, N_EDGES);
        fill_kernel<<<(N_EDGES + 255) / 256, 256, 0, stream>>>(src, dst, cursor, esrc, N_EDGES);
    }

    // --- weight conversion (all 6 layers, one launch) ---
    {
        WtDescs wd;
        const int fin[6] = {300, 200, 150, 100, 50, 25};
        for (int l = 0; l < 6; ++l)
            wd.d[l] = WtDesc{W[l], Wthi[l], Wtlo[l], fin[l], fout[l], KPin[l], NPl[l]};
        convert_w<<<dim3(320, 6), 256, 0, stream>>>(wd);
    }

    // --- features -> split bf16 padded ---
    {
        int total = N_NODES * 320;
        convert_x<300, 320><<<(total + 255) / 256, 256, 0, stream>>>(features, Xhi, Xlo, N_NODES);
    }

    const int gy = (N_NODES + 127) / 128;

    gemm_split<320><<<dim3(NPl[0] / 64, gy), 256, 0, stream>>>(Xhi, Xlo, Wthi[0], Wtlo[0], H, N_NODES, fout[0]);
    agg_act<0, 224><<<N_NODES, 64, 0, stream>>>(H, row_start, esrc, b[0], nullptr, Xhi, Xlo, fout[0]);

    gemm_split<224><<<dim3(NPl[1] / 64, gy), 256, 0, stream>>>(Xhi, Xlo, Wthi[1], Wtlo[1], H, N_NODES, fout[1]);
    agg_act<1, 160><<<N_NODES, 64, 0, stream>>>(H, row_start, esrc, b[1], nullptr, Xhi, Xlo, fout[1]);

    gemm_split<160><<<dim3(NPl[2] / 64, gy), 256, 0, stream>>>(Xhi, Xlo, Wthi[2], Wtlo[2], H, N_NODES, fout[2]);
    agg_act<0, 128><<<N_NODES, 64, 0, stream>>>(H, row_start, esrc, b[2], nullptr, Xhi, Xlo, fout[2]);

    gemm_split<128><<<dim3(NPl[3] / 64, gy), 256, 0, stream>>>(Xhi, Xlo, Wthi[3], Wtlo[3], H, N_NODES, fout[3]);
    agg_act<1, 64><<<N_NODES, 64, 0, stream>>>(H, row_start, esrc, b[3], nullptr, Xhi, Xlo, fout[3]);

    gemm_split<64><<<dim3(NPl[4] / 64, gy), 256, 0, stream>>>(Xhi, Xlo, Wthi[4], Wtlo[4], H, N_NODES, fout[4]);
    agg_act<0, 32><<<N_NODES, 64, 0, stream>>>(H, row_start, esrc, b[4], nullptr, Xhi, Xlo, fout[4]);

    gemm_split<32><<<dim3(NPl[5] / 64, gy), 256, 0, stream>>>(Xhi, Xlo, Wthi[5], Wtlo[5], H, N_NODES, fout[5]);
    agg_act<2, 0><<<N_NODES, 64, 0, stream>>>(H, row_start, esrc, b[5], (float*)d_out, nullptr, nullptr, fout[5]);

    (void)out_size; (void)n_in; (void)in_sizes;
}

// Round 4
// 413.392 us; speedup vs baseline: 1.8774x; 1.1465x over previous
//
#include <hip/hip_runtime.h>
#include <math.h>

#define N_NODES 50000
#define N_EDGES 262144

using short8 = __attribute__((ext_vector_type(8))) short;
using f32x4  = __attribute__((ext_vector_type(4))) float;

// ---------------------------------------------------------------------------
// bf16 split helpers (RNE)
// ---------------------------------------------------------------------------
__device__ __forceinline__ ushort bf16_rne(float x) {
    uint u = __float_as_uint(x);
    uint r = (u + 0x7FFFu + ((u >> 16) & 1u)) >> 16;
    return (ushort)r;
}
__device__ __forceinline__ float bf16_to_f32(ushort h) {
    return __uint_as_float(((uint)h) << 16);
}

// ---------------------------------------------------------------------------
// CSR build kernels
// ---------------------------------------------------------------------------
__global__ void zero_int_kernel(int* p, int n) {
    int i = blockIdx.x * 256 + threadIdx.x;
    if (i < n) p[i] = 0;
}

__global__ void count_kernel(const int* __restrict__ dst, int* __restrict__ deg, int E) {
    int e = blockIdx.x * 256 + threadIdx.x;
    if (e < E) atomicAdd(&deg[dst[e]], 1);
}

// --- 3-phase scan ---
__global__ __launch_bounds__(256) void scan_p1(const int* __restrict__ deg,
                                               int* __restrict__ local,
                                               int* __restrict__ blockSums, int n) {
    __shared__ int wsum[4];
    int b = blockIdx.x;
    int t = threadIdx.x;
    int i0 = b * 1024 + t * 4;
    int x0 = 0, x1 = 0, x2 = 0, x3 = 0;
    if (i0 + 3 < n) {
        int4 v = *(const int4*)(const void*)(deg + i0);
        x0 = v.x; x1 = v.y; x2 = v.z; x3 = v.w;
    } else {
        if (i0 + 0 < n) x0 = deg[i0 + 0];
        if (i0 + 1 < n) x1 = deg[i0 + 1];
        if (i0 + 2 < n) x2 = deg[i0 + 2];
        if (i0 + 3 < n) x3 = deg[i0 + 3];
    }
    int s = x0 + x1 + x2 + x3;
    int lane = t & 63;
    int wid = t >> 6;
    int incl = s;
    #pragma unroll
    for (int off = 1; off < 64; off <<= 1) {
        int u = __shfl_up(incl, off);
        if (lane >= off) incl += u;
    }
    if (lane == 63) wsum[wid] = incl;
    __syncthreads();
    int woff = 0;
    #pragma unroll
    for (int k = 0; k < 4; ++k)
        if (k < wid) woff += wsum[k];
    int texcl = woff + incl - s;
    if (i0 + 3 < n) {
        int4 o;
        o.x = texcl;
        o.y = texcl + x0;
        o.z = texcl + x0 + x1;
        o.w = texcl + x0 + x1 + x2;
        *(int4*)(void*)(local + i0) = o;
    } else {
        if (i0 + 0 < n) local[i0 + 0] = texcl;
        if (i0 + 1 < n) local[i0 + 1] = texcl + x0;
        if (i0 + 2 < n) local[i0 + 2] = texcl + x0 + x1;
        if (i0 + 3 < n) local[i0 + 3] = texcl + x0 + x1 + x2;
    }
    if (t == 0) blockSums[b] = wsum[0] + wsum[1] + wsum[2] + wsum[3];
}

__global__ __launch_bounds__(64) void scan_p2(int* __restrict__ blockSums, int nb) {
    int lane = threadIdx.x;
    int s = (lane < nb) ? blockSums[lane] : 0;
    int incl = s;
    #pragma unroll
    for (int off = 1; off < 64; off <<= 1) {
        int u = __shfl_up(incl, off);
        if (lane >= off) incl += u;
    }
    if (lane < nb) blockSums[lane] = incl - s;
}

__global__ __launch_bounds__(256) void scan_p3(const int* __restrict__ local,
                                               const int* __restrict__ blockSums,
                                               int* __restrict__ row_start,
                                               int* __restrict__ cursor, int n, int total) {
    int b = blockIdx.x;
    int off = blockSums[b];
    int i0 = b * 1024 + threadIdx.x * 4;
    if (i0 + 3 < n) {
        int4 v = *(const int4*)(const void*)(local + i0);
        v.x += off; v.y += off; v.z += off; v.w += off;
        *(int4*)(void*)(row_start + i0) = v;
        *(int4*)(void*)(cursor + i0) = v;
    } else {
        #pragma unroll
        for (int k = 0; k < 4; ++k)
            if (i0 + k < n) {
                int v = local[i0 + k] + off;
                row_start[i0 + k] = v;
                cursor[i0 + k] = v;
            }
    }
    if (b == 0 && threadIdx.x == 0) row_start[n] = total;
}

__global__ void fill_kernel(const int* __restrict__ src, const int* __restrict__ dst,
                            int* __restrict__ cursor, int* __restrict__ esrc, int E) {
    int e = blockIdx.x * 256 + threadIdx.x;
    if (e < E) {
        int d = dst[e];
        int pos = atomicAdd(&cursor[d], 1);
        esrc[pos] = src[e];
    }
}

// ---------------------------------------------------------------------------
// f32 -> (hi,lo) bf16 conversion
// ---------------------------------------------------------------------------
template <int F, int KP>
__global__ void convert_x(const float* __restrict__ X, ushort* __restrict__ hi,
                          ushort* __restrict__ lo, int M) {
    int idx = blockIdx.x * 256 + threadIdx.x;
    int row = idx / KP;
    int col = idx - row * KP;
    if (row >= M) return;
    float v = (col < F) ? X[(size_t)row * F + col] : 0.f;
    ushort h = bf16_rne(v);
    hi[idx] = h;
    lo[idx] = bf16_rne(v - bf16_to_f32(h));
}

struct WtDesc { const float* W; ushort* hi; ushort* lo; int K, N, KP, NP; };
struct WtDescs { WtDesc d[6]; };

__global__ void convert_w(WtDescs all) {
    WtDesc d = all.d[blockIdx.y];
    int total = d.NP * d.KP;
    for (int idx = blockIdx.x * 256 + threadIdx.x; idx < total; idx += gridDim.x * 256) {
        int n = idx / d.KP;
        int k = idx - n * d.KP;
        float v = (n < d.N && k < d.K) ? d.W[(size_t)k * d.N + n] : 0.f;
        ushort h = bf16_rne(v);
        d.hi[idx] = h;
        d.lo[idx] = bf16_rne(v - bf16_to_f32(h));
    }
}

// ---------------------------------------------------------------------------
// Split-bf16 MFMA GEMM, full-N per block: C[M,N] = A[M,KP] @ B^T[NP,KP]
// Block = 256 thr (4 waves), tile BM=128 x (NT*16). Each wave: 32 rows x NT*16.
// A is read from HBM exactly once per layer (no column-block re-fetch).
// ---------------------------------------------------------------------------
template <int KP, int NT>
__global__ __launch_bounds__(256) void gemm_split(const ushort* __restrict__ Ahi,
                                                  const ushort* __restrict__ Alo,
                                                  const ushort* __restrict__ Bhi,
                                                  const ushort* __restrict__ Blo,
                                                  float* __restrict__ C, int M, int N) {
    __shared__ __align__(16) ushort AsH[128][40];
    __shared__ __align__(16) ushort AsL[128][40];
    __shared__ __align__(16) ushort BsH[NT * 16][40];
    __shared__ __align__(16) ushort BsL[NT * 16][40];

    const int tid = threadIdx.x;
    const int lane = tid & 63;
    const int w = tid >> 6;
    const int brow = blockIdx.x * 128;

    f32x4 acc[2][NT];
    #pragma unroll
    for (int mt = 0; mt < 2; ++mt)
        #pragma unroll
        for (int nt = 0; nt < NT; ++nt)
            acc[mt][nt] = (f32x4){0.f, 0.f, 0.f, 0.f};

    const int ar = tid >> 1;
    const int aq = (tid & 1) * 2;
    const bool arow_ok = (brow + ar) < M;
    const size_t arow_off = (size_t)(brow + ar) * KP;

    const short8 zz = {0, 0, 0, 0, 0, 0, 0, 0};

    for (int kt = 0; kt < KP / 32; ++kt) {
        const int k0 = kt * 32;
        // A tile: 128 x 32 (hi, lo)
        #pragma unroll
        for (int qq = 0; qq < 2; ++qq) {
            int q = aq + qq;
            short8 vh = arow_ok ? *(const short8*)(const void*)(Ahi + arow_off + k0 + q * 8) : zz;
            short8 vl = arow_ok ? *(const short8*)(const void*)(Alo + arow_off + k0 + q * 8) : zz;
            *(short8*)(void*)&AsH[ar][q * 8] = vh;
            *(short8*)(void*)&AsL[ar][q * 8] = vl;
        }
        // B panel: NT*16 x 32 (hi, lo)
        for (int i = tid; i < NT * 64; i += 256) {
            int r = i >> 2;
            int q = i & 3;
            size_t boff = (size_t)r * KP + k0 + q * 8;
            *(short8*)(void*)&BsH[r][q * 8] = *(const short8*)(const void*)(Bhi + boff);
            *(short8*)(void*)&BsL[r][q * 8] = *(const short8*)(const void*)(Blo + boff);
        }
        __syncthreads();

        const int fr = lane & 15;
        const int fk = (lane >> 4) * 8;
        short8 ah[2], al[2];
        #pragma unroll
        for (int mt = 0; mt < 2; ++mt) {
            int r = w * 32 + mt * 16 + fr;
            ah[mt] = *(const short8*)(const void*)&AsH[r][fk];
            al[mt] = *(const short8*)(const void*)&AsL[r][fk];
        }
        #pragma unroll
        for (int nt = 0; nt < NT; ++nt) {
            int r = nt * 16 + fr;
            short8 bh = *(const short8*)(const void*)&BsH[r][fk];
            short8 bl = *(const short8*)(const void*)&BsL[r][fk];
            #pragma unroll
            for (int mt = 0; mt < 2; ++mt) {
                acc[mt][nt] = __builtin_amdgcn_mfma_f32_16x16x32_bf16(ah[mt], bh, acc[mt][nt], 0, 0, 0);
                acc[mt][nt] = __builtin_amdgcn_mfma_f32_16x16x32_bf16(ah[mt], bl, acc[mt][nt], 0, 0, 0);
                acc[mt][nt] = __builtin_amdgcn_mfma_f32_16x16x32_bf16(al[mt], bh, acc[mt][nt], 0, 0, 0);
            }
        }
        __syncthreads();
    }

    // epilogue: D layout col=lane&15, row=(lane>>4)*4+reg
    const int fr = lane & 15;
    const int fq = lane >> 4;
    #pragma unroll
    for (int mt = 0; mt < 2; ++mt)
        #pragma unroll
        for (int nt = 0; nt < NT; ++nt) {
            int col = nt * 16 + fr;
            if (col < N) {
                #pragma unroll
                for (int r = 0; r < 4; ++r) {
                    int row = brow + w * 32 + mt * 16 + fq * 4 + r;
                    if (row < M) C[(size_t)row * N + col] = acc[mt][nt][r];
                }
            }
        }
}

// ---------------------------------------------------------------------------
// Fused aggregation + bias + activation.
// ---------------------------------------------------------------------------
template <int ACT, int KPOUT>
__global__ __launch_bounds__(64) void agg_act(const float* __restrict__ H,
                                              const int* __restrict__ row_start,
                                              const int* __restrict__ esrc,
                                              const float* __restrict__ bias,
                                              float* __restrict__ outF,
                                              ushort* __restrict__ ohi,
                                              ushort* __restrict__ olo, int F) {
    int v = blockIdx.x;
    int lane = threadIdx.x;
    int e0 = row_start[v];
    int e1 = row_start[v + 1];

    float acc[4] = {0.f, 0.f, 0.f, 0.f};
    for (int e = e0; e < e1; ++e) {
        int s = esrc[e];
        const float* hr = H + (size_t)s * F;
        #pragma unroll
        for (int c = 0; c < 4; ++c) {
            int j = lane + (c << 6);
            if (j < F) acc[c] += hr[j];
        }
    }
    #pragma unroll
    for (int c = 0; c < 4; ++c) {
        int j = lane + (c << 6);
        if (j < F) acc[c] += bias[j];
    }

    float res[4] = {0.f, 0.f, 0.f, 0.f};
    if (ACT == 0) {
        #pragma unroll
        for (int c = 0; c < 4; ++c) {
            float x = acc[c];
            res[c] = (x >= 0.f) ? x : 0.01f * x;
        }
    } else {
        float m = -INFINITY;
        #pragma unroll
        for (int c = 0; c < 4; ++c) {
            int j = lane + (c << 6);
            if (j < F) m = fmaxf(m, acc[c]);
        }
        #pragma unroll
        for (int off = 32; off > 0; off >>= 1) m = fmaxf(m, __shfl_xor(m, off));
        float p[4];
        float s = 0.f;
        #pragma unroll
        for (int c = 0; c < 4; ++c) {
            int j = lane + (c << 6);
            if (j < F) { p[c] = expf(acc[c] - m); s += p[c]; } else p[c] = 0.f;
        }
        #pragma unroll
        for (int off = 32; off > 0; off >>= 1) s += __shfl_xor(s, off);
        if (ACT == 1) {
            float inv = 1.f / s;
            #pragma unroll
            for (int c = 0; c < 4; ++c) res[c] = p[c] * inv;
        } else {
            float ls = logf(s);
            #pragma unroll
            for (int c = 0; c < 4; ++c) res[c] = acc[c] - m - ls;
        }
    }

    if (KPOUT == 0) {
        float* orow = outF + (size_t)v * F;
        #pragma unroll
        for (int c = 0; c < 4; ++c) {
            int j = lane + (c << 6);
            if (j < F) orow[j] = res[c];
        }
    } else {
        size_t base = (size_t)v * KPOUT;
        #pragma unroll
        for (int c = 0; c < 4; ++c) {
            int j = lane + (c << 6);
            if (j < KPOUT) {
                float y = (j < F) ? res[c] : 0.f;
                ushort h = bf16_rne(y);
                ohi[base + j] = h;
                olo[base + j] = bf16_rne(y - bf16_to_f32(h));
            }
        }
    }
}

// ---------------------------------------------------------------------------
// Host launch
// ---------------------------------------------------------------------------
static inline size_t align_up(size_t x, size_t a) { return (x + a - 1) & ~(a - 1); }

extern "C" void kernel_launch(void* const* d_in, const int* in_sizes, int n_in,
                              void* d_out, int out_size, void* d_ws, size_t ws_size,
                              hipStream_t stream) {
    const float* features = (const float*)d_in[0];
    const int* src = (const int*)d_in[1];
    const int* dst = (const int*)d_in[2];
    const float* W[6];
    const float* b[6];
    for (int l = 0; l < 6; ++l) {
        W[l] = (const float*)d_in[3 + 2 * l];
        b[l] = (const float*)d_in[4 + 2 * l];
    }

    const int fout[6] = {200, 150, 100, 50, 25, 3};
    const int KPin[6] = {320, 224, 160, 128, 64, 32};
    const int NPl[6]  = {208, 160, 112, 64, 32, 16};   // NT*16

    // workspace layout
    char* ws = (char*)d_ws;
    size_t off = 0;
    int* row_start = (int*)(ws + off); off = align_up(off + (N_NODES + 1) * sizeof(int), 256);
    int* cursor    = (int*)(ws + off); off = align_up(off + (N_NODES + 1) * sizeof(int), 256);
    int* esrc      = (int*)(ws + off); off = align_up(off + N_EDGES * sizeof(int), 256);
    int* scan_loc  = (int*)(ws + off); off = align_up(off + N_NODES * sizeof(int), 256);
    int* blockSums = (int*)(ws + off); off = align_up(off + 64 * sizeof(int), 256);
    ushort* Wthi[6];
    ushort* Wtlo[6];
    for (int l = 0; l < 6; ++l) {
        Wthi[l] = (ushort*)(ws + off); off = align_up(off + (size_t)NPl[l] * KPin[l] * 2, 256);
        Wtlo[l] = (ushort*)(ws + off); off = align_up(off + (size_t)NPl[l] * KPin[l] * 2, 256);
    }
    ushort* Xhi = (ushort*)(ws + off); off = align_up(off + (size_t)N_NODES * 320 * 2, 256);
    ushort* Xlo = (ushort*)(ws + off); off = align_up(off + (size_t)N_NODES * 320 * 2, 256);
    float* H    = (float*)(ws + off);  off = align_up(off + (size_t)N_NODES * 200 * 4, 256);
    (void)ws_size;

    // --- build CSR by dst ---
    {
        const int nb = (N_NODES + 1023) / 1024;  // 49
        zero_int_kernel<<<(N_NODES + 255) / 256, 256, 0, stream>>>(cursor, N_NODES);
        count_kernel<<<(N_EDGES + 255) / 256, 256, 0, stream>>>(dst, cursor, N_EDGES);
        scan_p1<<<nb, 256, 0, stream>>>(cursor, scan_loc, blockSums, N_NODES);
        scan_p2<<<1, 64, 0, stream>>>(blockSums, nb);
        scan_p3<<<nb, 256, 0, stream>>>(scan_loc, blockSums, row_start, cursor, N_NODES, N_EDGES);
        fill_kernel<<<(N_EDGES + 255) / 256, 256, 0, stream>>>(src, dst, cursor, esrc, N_EDGES);
    }

    // --- weight conversion ---
    {
        WtDescs wd;
        const int fin[6] = {300, 200, 150, 100, 50, 25};
        for (int l = 0; l < 6; ++l)
            wd.d[l] = WtDesc{W[l], Wthi[l], Wtlo[l], fin[l], fout[l], KPin[l], NPl[l]};
        convert_w<<<dim3(320, 6), 256, 0, stream>>>(wd);
    }

    // --- features -> split bf16 padded ---
    {
        int total = N_NODES * 320;
        convert_x<300, 320><<<(total + 255) / 256, 256, 0, stream>>>(features, Xhi, Xlo, N_NODES);
    }

    const int gy = (N_NODES + 127) / 128;  // 391

    gemm_split<320, 13><<<gy, 256, 0, stream>>>(Xhi, Xlo, Wthi[0], Wtlo[0], H, N_NODES, fout[0]);
    agg_act<0, 224><<<N_NODES, 64, 0, stream>>>(H, row_start, esrc, b[0], nullptr, Xhi, Xlo, fout[0]);

    gemm_split<224, 10><<<gy, 256, 0, stream>>>(Xhi, Xlo, Wthi[1], Wtlo[1], H, N_NODES, fout[1]);
    agg_act<1, 160><<<N_NODES, 64, 0, stream>>>(H, row_start, esrc, b[1], nullptr, Xhi, Xlo, fout[1]);

    gemm_split<160, 7><<<gy, 256, 0, stream>>>(Xhi, Xlo, Wthi[2], Wtlo[2], H, N_NODES, fout[2]);
    agg_act<0, 128><<<N_NODES, 64, 0, stream>>>(H, row_start, esrc, b[2], nullptr, Xhi, Xlo, fout[2]);

    gemm_split<128, 4><<<gy, 256, 0, stream>>>(Xhi, Xlo, Wthi[3], Wtlo[3], H, N_NODES, fout[3]);
    agg_act<1, 64><<<N_NODES, 64, 0, stream>>>(H, row_start, esrc, b[3], nullptr, Xhi, Xlo, fout[3]);

    gemm_split<64, 2><<<gy, 256, 0, stream>>>(Xhi, Xlo, Wthi[4], Wtlo[4], H, N_NODES, fout[4]);
    agg_act<0, 32><<<N_NODES, 64, 0, stream>>>(H, row_start, esrc, b[4], nullptr, Xhi, Xlo, fout[4]);

    gemm_split<32, 1><<<gy, 256, 0, stream>>>(Xhi, Xlo, Wthi[5], Wtlo[5], H, N_NODES, fout[5]);
    agg_act<2, 0><<<N_NODES, 64, 0, stream>>>(H, row_start, esrc, b[5], (float*)d_out, nullptr, nullptr, fout[5]);

    (void)out_size; (void)n_in; (void)in_sizes;
}

// Round 5
// 348.319 us; speedup vs baseline: 2.2281x; 1.1868x over previous
//
#include <hip/hip_runtime.h>
#include <math.h>

#define N_NODES 50000
#define N_EDGES 262144

using short8 = __attribute__((ext_vector_type(8))) short;
using f32x4  = __attribute__((ext_vector_type(4))) float;
using u16x4  = __attribute__((ext_vector_type(4))) unsigned short;

// ---------------------------------------------------------------------------
// bf16 split helpers (RNE)
// ---------------------------------------------------------------------------
__device__ __forceinline__ ushort bf16_rne(float x) {
    uint u = __float_as_uint(x);
    uint r = (u + 0x7FFFu + ((u >> 16) & 1u)) >> 16;
    return (ushort)r;
}
__device__ __forceinline__ float bf16_to_f32(ushort h) {
    return __uint_as_float(((uint)h) << 16);
}

// ---------------------------------------------------------------------------
// CSR build kernels
// ---------------------------------------------------------------------------
__global__ void zero_int_kernel(int* p, int n) {
    int i = blockIdx.x * 256 + threadIdx.x;
    if (i < n) p[i] = 0;
}

__global__ void count_kernel(const int* __restrict__ dst, int* __restrict__ deg, int E) {
    int e = blockIdx.x * 256 + threadIdx.x;
    if (e < E) atomicAdd(&deg[dst[e]], 1);
}

// --- 3-phase scan ---
__global__ __launch_bounds__(256) void scan_p1(const int* __restrict__ deg,
                                               int* __restrict__ local,
                                               int* __restrict__ blockSums, int n) {
    __shared__ int wsum[4];
    int b = blockIdx.x;
    int t = threadIdx.x;
    int i0 = b * 1024 + t * 4;
    int x0 = 0, x1 = 0, x2 = 0, x3 = 0;
    if (i0 + 3 < n) {
        int4 v = *(const int4*)(const void*)(deg + i0);
        x0 = v.x; x1 = v.y; x2 = v.z; x3 = v.w;
    } else {
        if (i0 + 0 < n) x0 = deg[i0 + 0];
        if (i0 + 1 < n) x1 = deg[i0 + 1];
        if (i0 + 2 < n) x2 = deg[i0 + 2];
        if (i0 + 3 < n) x3 = deg[i0 + 3];
    }
    int s = x0 + x1 + x2 + x3;
    int lane = t & 63;
    int wid = t >> 6;
    int incl = s;
    #pragma unroll
    for (int off = 1; off < 64; off <<= 1) {
        int u = __shfl_up(incl, off);
        if (lane >= off) incl += u;
    }
    if (lane == 63) wsum[wid] = incl;
    __syncthreads();
    int woff = 0;
    #pragma unroll
    for (int k = 0; k < 4; ++k)
        if (k < wid) woff += wsum[k];
    int texcl = woff + incl - s;
    if (i0 + 3 < n) {
        int4 o;
        o.x = texcl;
        o.y = texcl + x0;
        o.z = texcl + x0 + x1;
        o.w = texcl + x0 + x1 + x2;
        *(int4*)(void*)(local + i0) = o;
    } else {
        if (i0 + 0 < n) local[i0 + 0] = texcl;
        if (i0 + 1 < n) local[i0 + 1] = texcl + x0;
        if (i0 + 2 < n) local[i0 + 2] = texcl + x0 + x1;
        if (i0 + 3 < n) local[i0 + 3] = texcl + x0 + x1 + x2;
    }
    if (t == 0) blockSums[b] = wsum[0] + wsum[1] + wsum[2] + wsum[3];
}

__global__ __launch_bounds__(64) void scan_p2(int* __restrict__ blockSums, int nb) {
    int lane = threadIdx.x;
    int s = (lane < nb) ? blockSums[lane] : 0;
    int incl = s;
    #pragma unroll
    for (int off = 1; off < 64; off <<= 1) {
        int u = __shfl_up(incl, off);
        if (lane >= off) incl += u;
    }
    if (lane < nb) blockSums[lane] = incl - s;
}

__global__ __launch_bounds__(256) void scan_p3(const int* __restrict__ local,
                                               const int* __restrict__ blockSums,
                                               int* __restrict__ row_start,
                                               int* __restrict__ cursor, int n, int total) {
    int b = blockIdx.x;
    int off = blockSums[b];
    int i0 = b * 1024 + threadIdx.x * 4;
    if (i0 + 3 < n) {
        int4 v = *(const int4*)(const void*)(local + i0);
        v.x += off; v.y += off; v.z += off; v.w += off;
        *(int4*)(void*)(row_start + i0) = v;
        *(int4*)(void*)(cursor + i0) = v;
    } else {
        #pragma unroll
        for (int k = 0; k < 4; ++k)
            if (i0 + k < n) {
                int v = local[i0 + k] + off;
                row_start[i0 + k] = v;
                cursor[i0 + k] = v;
            }
    }
    if (b == 0 && threadIdx.x == 0) row_start[n] = total;
}

__global__ void fill_kernel(const int* __restrict__ src, const int* __restrict__ dst,
                            int* __restrict__ cursor, int* __restrict__ esrc, int E) {
    int e = blockIdx.x * 256 + threadIdx.x;
    if (e < E) {
        int d = dst[e];
        int pos = atomicAdd(&cursor[d], 1);
        esrc[pos] = src[e];
    }
}

// ---------------------------------------------------------------------------
// features f32 [N][300] -> split-bf16 [N][320], float4/ushort4 vectorized
// ---------------------------------------------------------------------------
__global__ void convert_x4(const float* __restrict__ X, ushort* __restrict__ hi,
                           ushort* __restrict__ lo) {
    int idx = blockIdx.x * 256 + threadIdx.x;  // N_NODES*80 chunk-of-4 jobs
    if (idx >= N_NODES * 80) return;
    int row = idx / 80;
    int c = idx - row * 80;
    u16x4 h4 = {0, 0, 0, 0}, l4 = {0, 0, 0, 0};
    if (c < 75) {
        float4 v = *(const float4*)(const void*)(X + (size_t)row * 300 + c * 4);
        float vv[4] = {v.x, v.y, v.z, v.w};
        #pragma unroll
        for (int k = 0; k < 4; ++k) {
            ushort h = bf16_rne(vv[k]);
            h4[k] = h;
            l4[k] = bf16_rne(vv[k] - bf16_to_f32(h));
        }
    }
    size_t o = (size_t)row * 320 + c * 4;
    *(u16x4*)(void*)(hi + o) = h4;
    *(u16x4*)(void*)(lo + o) = l4;
}

struct WtDesc { const float* W; ushort* hi; ushort* lo; int K, N, KP, NP; };
struct WtDescs { WtDesc d[6]; };

__global__ void convert_w(WtDescs all) {
    WtDesc d = all.d[blockIdx.y];
    int total = d.NP * d.KP;
    for (int idx = blockIdx.x * 256 + threadIdx.x; idx < total; idx += gridDim.x * 256) {
        int n = idx / d.KP;
        int k = idx - n * d.KP;
        float v = (n < d.N && k < d.K) ? d.W[(size_t)k * d.N + n] : 0.f;
        ushort h = bf16_rne(v);
        d.hi[idx] = h;
        d.lo[idx] = bf16_rne(v - bf16_to_f32(h));
    }
}

// ---------------------------------------------------------------------------
// Split-bf16 MFMA GEMM, full-N per block: C[M, strideC] = A[M,KP] @ B^T
// Writes all cols < strideC (pad cols are exact 0 since B pad rows are 0).
// ---------------------------------------------------------------------------
template <int KP, int NT>
__global__ __launch_bounds__(256) void gemm_split(const ushort* __restrict__ Ahi,
                                                  const ushort* __restrict__ Alo,
                                                  const ushort* __restrict__ Bhi,
                                                  const ushort* __restrict__ Blo,
                                                  float* __restrict__ C, int M, int strideC) {
    __shared__ __align__(16) ushort AsH[128][40];
    __shared__ __align__(16) ushort AsL[128][40];
    __shared__ __align__(16) ushort BsH[NT * 16][40];
    __shared__ __align__(16) ushort BsL[NT * 16][40];

    const int tid = threadIdx.x;
    const int lane = tid & 63;
    const int w = tid >> 6;
    const int brow = blockIdx.x * 128;

    f32x4 acc[2][NT];
    #pragma unroll
    for (int mt = 0; mt < 2; ++mt)
        #pragma unroll
        for (int nt = 0; nt < NT; ++nt)
            acc[mt][nt] = (f32x4){0.f, 0.f, 0.f, 0.f};

    const int ar = tid >> 1;
    const int aq = (tid & 1) * 2;
    const bool arow_ok = (brow + ar) < M;
    const size_t arow_off = (size_t)(brow + ar) * KP;

    const short8 zz = {0, 0, 0, 0, 0, 0, 0, 0};

    for (int kt = 0; kt < KP / 32; ++kt) {
        const int k0 = kt * 32;
        #pragma unroll
        for (int qq = 0; qq < 2; ++qq) {
            int q = aq + qq;
            short8 vh = arow_ok ? *(const short8*)(const void*)(Ahi + arow_off + k0 + q * 8) : zz;
            short8 vl = arow_ok ? *(const short8*)(const void*)(Alo + arow_off + k0 + q * 8) : zz;
            *(short8*)(void*)&AsH[ar][q * 8] = vh;
            *(short8*)(void*)&AsL[ar][q * 8] = vl;
        }
        for (int i = tid; i < NT * 64; i += 256) {
            int r = i >> 2;
            int q = i & 3;
            size_t boff = (size_t)r * KP + k0 + q * 8;
            *(short8*)(void*)&BsH[r][q * 8] = *(const short8*)(const void*)(Bhi + boff);
            *(short8*)(void*)&BsL[r][q * 8] = *(const short8*)(const void*)(Blo + boff);
        }
        __syncthreads();

        const int fr = lane & 15;
        const int fk = (lane >> 4) * 8;
        short8 ah[2], al[2];
        #pragma unroll
        for (int mt = 0; mt < 2; ++mt) {
            int r = w * 32 + mt * 16 + fr;
            ah[mt] = *(const short8*)(const void*)&AsH[r][fk];
            al[mt] = *(const short8*)(const void*)&AsL[r][fk];
        }
        #pragma unroll
        for (int nt = 0; nt < NT; ++nt) {
            int r = nt * 16 + fr;
            short8 bh = *(const short8*)(const void*)&BsH[r][fk];
            short8 bl = *(const short8*)(const void*)&BsL[r][fk];
            #pragma unroll
            for (int mt = 0; mt < 2; ++mt) {
                acc[mt][nt] = __builtin_amdgcn_mfma_f32_16x16x32_bf16(ah[mt], bh, acc[mt][nt], 0, 0, 0);
                acc[mt][nt] = __builtin_amdgcn_mfma_f32_16x16x32_bf16(ah[mt], bl, acc[mt][nt], 0, 0, 0);
                acc[mt][nt] = __builtin_amdgcn_mfma_f32_16x16x32_bf16(al[mt], bh, acc[mt][nt], 0, 0, 0);
            }
        }
        __syncthreads();
    }

    const int fr = lane & 15;
    const int fq = lane >> 4;
    #pragma unroll
    for (int mt = 0; mt < 2; ++mt)
        #pragma unroll
        for (int nt = 0; nt < NT; ++nt) {
            int col = nt * 16 + fr;
            if (col < strideC) {
                #pragma unroll
                for (int r = 0; r < 4; ++r) {
                    int row = brow + w * 32 + mt * 16 + fq * 4 + r;
                    if (row < M) C[(size_t)row * strideC + col] = acc[mt][nt][r];
                }
            }
        }
}

// ---------------------------------------------------------------------------
// Fused aggregation + bias + activation. float4 gather, 4-edge unroll.
// One wave per node, 4 nodes per 256-block. H rows padded to FP (pad = 0).
// ACT: 0 leaky, 1 softmax, 2 log_softmax.
// ---------------------------------------------------------------------------
__device__ __forceinline__ float4 f4_add(float4 a, float4 b) {
    a.x += b.x; a.y += b.y; a.z += b.z; a.w += b.w;
    return a;
}

template <int ACT, int F, int FP, int KPOUT>
__global__ __launch_bounds__(256) void agg_act(const float* __restrict__ H,
                                               const int* __restrict__ row_start,
                                               const int* __restrict__ esrc,
                                               const float* __restrict__ bias,
                                               float* __restrict__ outF,
                                               ushort* __restrict__ ohi,
                                               ushort* __restrict__ olo) {
    constexpr int CPN = FP / 4;  // float4 chunks per node row
    const int wid = threadIdx.x >> 6;
    const int lane = threadIdx.x & 63;
    const int v = blockIdx.x * 4 + wid;
    if (v >= N_NODES) return;

    const int e0 = row_start[v];
    const int e1 = row_start[v + 1];
    const bool al = lane < CPN;
    const float4* Hv = (const float4*)H;

    float4 acc = {0.f, 0.f, 0.f, 0.f};
    int e = e0;
    for (; e + 4 <= e1; e += 4) {
        int s0 = esrc[e + 0];
        int s1 = esrc[e + 1];
        int s2 = esrc[e + 2];
        int s3 = esrc[e + 3];
        if (al) {
            float4 v0 = Hv[(size_t)s0 * CPN + lane];
            float4 v1 = Hv[(size_t)s1 * CPN + lane];
            float4 v2 = Hv[(size_t)s2 * CPN + lane];
            float4 v3 = Hv[(size_t)s3 * CPN + lane];
            acc = f4_add(acc, f4_add(f4_add(v0, v1), f4_add(v2, v3)));
        }
    }
    for (; e < e1; ++e) {
        int s = esrc[e];
        if (al) acc = f4_add(acc, Hv[(size_t)s * CPN + lane]);
    }

    const int jb = lane * 4;
    float a[4] = {acc.x, acc.y, acc.z, acc.w};
    #pragma unroll
    for (int k = 0; k < 4; ++k) {
        int j = jb + k;
        a[k] += (al && j < F) ? bias[j] : 0.f;
    }

    float res[4] = {0.f, 0.f, 0.f, 0.f};
    if (ACT == 0) {
        #pragma unroll
        for (int k = 0; k < 4; ++k)
            res[k] = (a[k] >= 0.f) ? a[k] : 0.01f * a[k];
    } else {
        float m = -INFINITY;
        #pragma unroll
        for (int k = 0; k < 4; ++k) {
            int j = jb + k;
            if (al && j < F) m = fmaxf(m, a[k]);
        }
        #pragma unroll
        for (int off = 32; off > 0; off >>= 1) m = fmaxf(m, __shfl_xor(m, off));
        float p[4];
        float s = 0.f;
        #pragma unroll
        for (int k = 0; k < 4; ++k) {
            int j = jb + k;
            if (al && j < F) { p[k] = expf(a[k] - m); s += p[k]; } else p[k] = 0.f;
        }
        #pragma unroll
        for (int off = 32; off > 0; off >>= 1) s += __shfl_xor(s, off);
        if (ACT == 1) {
            float inv = 1.f / s;
            #pragma unroll
            for (int k = 0; k < 4; ++k) res[k] = p[k] * inv;
        } else {
            float ls = logf(s);
            #pragma unroll
            for (int k = 0; k < 4; ++k) res[k] = a[k] - m - ls;
        }
    }

    if (KPOUT == 0) {
        float* orow = outF + (size_t)v * F;
        #pragma unroll
        for (int k = 0; k < 4; ++k) {
            int j = jb + k;
            if (al && j < F) orow[j] = res[k];
        }
    } else {
        if (lane < KPOUT / 4) {
            u16x4 h4 = {0, 0, 0, 0}, l4 = {0, 0, 0, 0};
            #pragma unroll
            for (int k = 0; k < 4; ++k) {
                int j = jb + k;
                float y = (j < F) ? res[k] : 0.f;
                ushort h = bf16_rne(y);
                h4[k] = h;
                l4[k] = bf16_rne(y - bf16_to_f32(h));
            }
            size_t o = (size_t)v * KPOUT + jb;
            *(u16x4*)(void*)(ohi + o) = h4;
            *(u16x4*)(void*)(olo + o) = l4;
        }
    }
}

// ---------------------------------------------------------------------------
// Host launch
// ---------------------------------------------------------------------------
static inline size_t align_up(size_t x, size_t a) { return (x + a - 1) & ~(a - 1); }

extern "C" void kernel_launch(void* const* d_in, const int* in_sizes, int n_in,
                              void* d_out, int out_size, void* d_ws, size_t ws_size,
                              hipStream_t stream) {
    const float* features = (const float*)d_in[0];
    const int* src = (const int*)d_in[1];
    const int* dst = (const int*)d_in[2];
    const float* W[6];
    const float* b[6];
    for (int l = 0; l < 6; ++l) {
        W[l] = (const float*)d_in[3 + 2 * l];
        b[l] = (const float*)d_in[4 + 2 * l];
    }

    const int fout[6] = {200, 150, 100, 50, 25, 3};
    const int KPin[6] = {320, 224, 160, 128, 64, 32};
    const int NPl[6]  = {208, 160, 112, 64, 32, 16};   // NT*16
    const int FPl[6]  = {200, 152, 100, 52, 28, 4};    // H row stride (align4)

    // workspace layout
    char* ws = (char*)d_ws;
    size_t off = 0;
    int* row_start = (int*)(ws + off); off = align_up(off + (N_NODES + 1) * sizeof(int), 256);
    int* cursor    = (int*)(ws + off); off = align_up(off + (N_NODES + 1) * sizeof(int), 256);
    int* esrc      = (int*)(ws + off); off = align_up(off + N_EDGES * sizeof(int), 256);
    int* scan_loc  = (int*)(ws + off); off = align_up(off + N_NODES * sizeof(int), 256);
    int* blockSums = (int*)(ws + off); off = align_up(off + 64 * sizeof(int), 256);
    ushort* Wthi[6];
    ushort* Wtlo[6];
    for (int l = 0; l < 6; ++l) {
        Wthi[l] = (ushort*)(ws + off); off = align_up(off + (size_t)NPl[l] * KPin[l] * 2, 256);
        Wtlo[l] = (ushort*)(ws + off); off = align_up(off + (size_t)NPl[l] * KPin[l] * 2, 256);
    }
    ushort* Xhi = (ushort*)(ws + off); off = align_up(off + (size_t)N_NODES * 320 * 2, 256);
    ushort* Xlo = (ushort*)(ws + off); off = align_up(off + (size_t)N_NODES * 320 * 2, 256);
    float* H    = (float*)(ws + off);  off = align_up(off + (size_t)N_NODES * 200 * 4, 256);
    (void)ws_size;

    // --- build CSR by dst ---
    {
        const int nb = (N_NODES + 1023) / 1024;  // 49
        zero_int_kernel<<<(N_NODES + 255) / 256, 256, 0, stream>>>(cursor, N_NODES);
        count_kernel<<<(N_EDGES + 255) / 256, 256, 0, stream>>>(dst, cursor, N_EDGES);
        scan_p1<<<nb, 256, 0, stream>>>(cursor, scan_loc, blockSums, N_NODES);
        scan_p2<<<1, 64, 0, stream>>>(blockSums, nb);
        scan_p3<<<nb, 256, 0, stream>>>(scan_loc, blockSums, row_start, cursor, N_NODES, N_EDGES);
        fill_kernel<<<(N_EDGES + 255) / 256, 256, 0, stream>>>(src, dst, cursor, esrc, N_EDGES);
    }

    // --- weight conversion ---
    {
        WtDescs wd;
        const int fin[6] = {300, 200, 150, 100, 50, 25};
        for (int l = 0; l < 6; ++l)
            wd.d[l] = WtDesc{W[l], Wthi[l], Wtlo[l], fin[l], fout[l], KPin[l], NPl[l]};
        convert_w<<<dim3(320, 6), 256, 0, stream>>>(wd);
    }

    // --- features -> split bf16 padded (vectorized) ---
    convert_x4<<<(N_NODES * 80 + 255) / 256, 256, 0, stream>>>(features, Xhi, Xlo);

    const int gy = (N_NODES + 127) / 128;  // 391
    const int ga = (N_NODES + 3) / 4;      // 12500

    gemm_split<320, 13><<<gy, 256, 0, stream>>>(Xhi, Xlo, Wthi[0], Wtlo[0], H, N_NODES, FPl[0]);
    agg_act<0, 200, 200, 224><<<ga, 256, 0, stream>>>(H, row_start, esrc, b[0], nullptr, Xhi, Xlo);

    gemm_split<224, 10><<<gy, 256, 0, stream>>>(Xhi, Xlo, Wthi[1], Wtlo[1], H, N_NODES, FPl[1]);
    agg_act<1, 150, 152, 160><<<ga, 256, 0, stream>>>(H, row_start, esrc, b[1], nullptr, Xhi, Xlo);

    gemm_split<160, 7><<<gy, 256, 0, stream>>>(Xhi, Xlo, Wthi[2], Wtlo[2], H, N_NODES, FPl[2]);
    agg_act<0, 100, 100, 128><<<ga, 256, 0, stream>>>(H, row_start, esrc, b[2], nullptr, Xhi, Xlo);

    gemm_split<128, 4><<<gy, 256, 0, stream>>>(Xhi, Xlo, Wthi[3], Wtlo[3], H, N_NODES, FPl[3]);
    agg_act<1, 50, 52, 64><<<ga, 256, 0, stream>>>(H, row_start, esrc, b[3], nullptr, Xhi, Xlo);

    gemm_split<64, 2><<<gy, 256, 0, stream>>>(Xhi, Xlo, Wthi[4], Wtlo[4], H, N_NODES, FPl[4]);
    agg_act<0, 25, 28, 32><<<ga, 256, 0, stream>>>(H, row_start, esrc, b[4], nullptr, Xhi, Xlo);

    gemm_split<32, 1><<<gy, 256, 0, stream>>>(Xhi, Xlo, Wthi[5], Wtlo[5], H, N_NODES, FPl[5]);
    agg_act<2, 3, 4, 0><<<ga, 256, 0, stream>>>(H, row_start, esrc, b[5], (float*)d_out, nullptr, nullptr);

    (void)out_size; (void)n_in; (void)in_sizes;
}

// Round 6
// 342.153 us; speedup vs baseline: 2.2683x; 1.0180x over previous
//
#include <hip/hip_runtime.h>
#include <math.h>

#define N_NODES 50000
#define N_EDGES 262144

using short8 = __attribute__((ext_vector_type(8))) short;
using f32x4  = __attribute__((ext_vector_type(4))) float;
using u16x4  = __attribute__((ext_vector_type(4))) unsigned short;

// ---------------------------------------------------------------------------
// bf16 split helpers (RNE)
// ---------------------------------------------------------------------------
__device__ __forceinline__ ushort bf16_rne(float x) {
    uint u = __float_as_uint(x);
    uint r = (u + 0x7FFFu + ((u >> 16) & 1u)) >> 16;
    return (ushort)r;
}
__device__ __forceinline__ float bf16_to_f32(ushort h) {
    return __uint_as_float(((uint)h) << 16);
}

// ---------------------------------------------------------------------------
// CSR build kernels
// ---------------------------------------------------------------------------
__global__ void zero_int_kernel(int* p, int n) {
    int i = blockIdx.x * 256 + threadIdx.x;
    if (i < n) p[i] = 0;
}

__global__ void count_kernel(const int* __restrict__ dst, int* __restrict__ deg, int E) {
    int e = blockIdx.x * 256 + threadIdx.x;
    if (e < E) atomicAdd(&deg[dst[e]], 1);
}

// --- 3-phase scan ---
__global__ __launch_bounds__(256) void scan_p1(const int* __restrict__ deg,
                                               int* __restrict__ local,
                                               int* __restrict__ blockSums, int n) {
    __shared__ int wsum[4];
    int b = blockIdx.x;
    int t = threadIdx.x;
    int i0 = b * 1024 + t * 4;
    int x0 = 0, x1 = 0, x2 = 0, x3 = 0;
    if (i0 + 3 < n) {
        int4 v = *(const int4*)(const void*)(deg + i0);
        x0 = v.x; x1 = v.y; x2 = v.z; x3 = v.w;
    } else {
        if (i0 + 0 < n) x0 = deg[i0 + 0];
        if (i0 + 1 < n) x1 = deg[i0 + 1];
        if (i0 + 2 < n) x2 = deg[i0 + 2];
        if (i0 + 3 < n) x3 = deg[i0 + 3];
    }
    int s = x0 + x1 + x2 + x3;
    int lane = t & 63;
    int wid = t >> 6;
    int incl = s;
    #pragma unroll
    for (int off = 1; off < 64; off <<= 1) {
        int u = __shfl_up(incl, off);
        if (lane >= off) incl += u;
    }
    if (lane == 63) wsum[wid] = incl;
    __syncthreads();
    int woff = 0;
    #pragma unroll
    for (int k = 0; k < 4; ++k)
        if (k < wid) woff += wsum[k];
    int texcl = woff + incl - s;
    if (i0 + 3 < n) {
        int4 o;
        o.x = texcl;
        o.y = texcl + x0;
        o.z = texcl + x0 + x1;
        o.w = texcl + x0 + x1 + x2;
        *(int4*)(void*)(local + i0) = o;
    } else {
        if (i0 + 0 < n) local[i0 + 0] = texcl;
        if (i0 + 1 < n) local[i0 + 1] = texcl + x0;
        if (i0 + 2 < n) local[i0 + 2] = texcl + x0 + x1;
        if (i0 + 3 < n) local[i0 + 3] = texcl + x0 + x1 + x2;
    }
    if (t == 0) blockSums[b] = wsum[0] + wsum[1] + wsum[2] + wsum[3];
}

__global__ __launch_bounds__(64) void scan_p2(int* __restrict__ blockSums, int nb) {
    int lane = threadIdx.x;
    int s = (lane < nb) ? blockSums[lane] : 0;
    int incl = s;
    #pragma unroll
    for (int off = 1; off < 64; off <<= 1) {
        int u = __shfl_up(incl, off);
        if (lane >= off) incl += u;
    }
    if (lane < nb) blockSums[lane] = incl - s;
}

__global__ __launch_bounds__(256) void scan_p3(const int* __restrict__ local,
                                               const int* __restrict__ blockSums,
                                               int* __restrict__ row_start,
                                               int* __restrict__ cursor, int n, int total) {
    int b = blockIdx.x;
    int off = blockSums[b];
    int i0 = b * 1024 + threadIdx.x * 4;
    if (i0 + 3 < n) {
        int4 v = *(const int4*)(const void*)(local + i0);
        v.x += off; v.y += off; v.z += off; v.w += off;
        *(int4*)(void*)(row_start + i0) = v;
        *(int4*)(void*)(cursor + i0) = v;
    } else {
        #pragma unroll
        for (int k = 0; k < 4; ++k)
            if (i0 + k < n) {
                int v = local[i0 + k] + off;
                row_start[i0 + k] = v;
                cursor[i0 + k] = v;
            }
    }
    if (b == 0 && threadIdx.x == 0) row_start[n] = total;
}

__global__ void fill_kernel(const int* __restrict__ src, const int* __restrict__ dst,
                            int* __restrict__ cursor, int* __restrict__ esrc, int E) {
    int e = blockIdx.x * 256 + threadIdx.x;
    if (e < E) {
        int d = dst[e];
        int pos = atomicAdd(&cursor[d], 1);
        esrc[pos] = src[e];
    }
}

// ---------------------------------------------------------------------------
// features f32 [N][300] -> split-bf16 [N][320], float4/ushort4 vectorized
// ---------------------------------------------------------------------------
__global__ void convert_x4(const float* __restrict__ X, ushort* __restrict__ hi,
                           ushort* __restrict__ lo) {
    int idx = blockIdx.x * 256 + threadIdx.x;
    if (idx >= N_NODES * 80) return;
    int row = idx / 80;
    int c = idx - row * 80;
    u16x4 h4 = {0, 0, 0, 0}, l4 = {0, 0, 0, 0};
    if (c < 75) {
        float4 v = *(const float4*)(const void*)(X + (size_t)row * 300 + c * 4);
        float vv[4] = {v.x, v.y, v.z, v.w};
        #pragma unroll
        for (int k = 0; k < 4; ++k) {
            ushort h = bf16_rne(vv[k]);
            h4[k] = h;
            l4[k] = bf16_rne(vv[k] - bf16_to_f32(h));
        }
    }
    size_t o = (size_t)row * 320 + c * 4;
    *(u16x4*)(void*)(hi + o) = h4;
    *(u16x4*)(void*)(lo + o) = l4;
}

struct WtDesc { const float* W; ushort* hi; ushort* lo; int K, N, KP, NP; };
struct WtDescs { WtDesc d[6]; };

__global__ void convert_w(WtDescs all) {
    WtDesc d = all.d[blockIdx.y];
    int total = d.NP * d.KP;
    for (int idx = blockIdx.x * 256 + threadIdx.x; idx < total; idx += gridDim.x * 256) {
        int n = idx / d.KP;
        int k = idx - n * d.KP;
        float v = (n < d.N && k < d.K) ? d.W[(size_t)k * d.N + n] : 0.f;
        ushort h = bf16_rne(v);
        d.hi[idx] = h;
        d.lo[idx] = bf16_rne(v - bf16_to_f32(h));
    }
}

// ---------------------------------------------------------------------------
// Split-bf16 MFMA GEMM, full-N per block, register-prefetch pipeline.
// C[M, strideC] = A[M,KP] @ B^T. Pad cols are exact 0 (B pad rows zero).
// ---------------------------------------------------------------------------
template <int KP, int NT>
__global__ __launch_bounds__(256) void gemm_split(const ushort* __restrict__ Ahi,
                                                  const ushort* __restrict__ Alo,
                                                  const ushort* __restrict__ Bhi,
                                                  const ushort* __restrict__ Blo,
                                                  float* __restrict__ C, int M, int strideC) {
    __shared__ __align__(16) ushort AsH[128][40];
    __shared__ __align__(16) ushort AsL[128][40];
    __shared__ __align__(16) ushort BsH[NT * 16][40];
    __shared__ __align__(16) ushort BsL[NT * 16][40];

    constexpr int NK = KP / 32;
    constexpr int BCH = (NT * 64 + 255) / 256;  // B reg-chunks per thread

    const int tid = threadIdx.x;
    const int lane = tid & 63;
    const int w = tid >> 6;
    const int brow = blockIdx.x * 128;

    f32x4 acc[2][NT];
    #pragma unroll
    for (int mt = 0; mt < 2; ++mt)
        #pragma unroll
        for (int nt = 0; nt < NT; ++nt)
            acc[mt][nt] = (f32x4){0.f, 0.f, 0.f, 0.f};

    const int ar = tid >> 1;
    const int aq = (tid & 1) * 2;
    const bool arow_ok = (brow + ar) < M;
    const size_t arow_off = (size_t)(brow + ar) * KP;

    const short8 zz = {0, 0, 0, 0, 0, 0, 0, 0};

    short8 rAh[2], rAl[2], rBh[BCH], rBl[BCH];

    auto load_regs = [&](int kt) {
        const int k0 = kt * 32;
        #pragma unroll
        for (int qq = 0; qq < 2; ++qq) {
            int q = aq + qq;
            rAh[qq] = arow_ok ? *(const short8*)(const void*)(Ahi + arow_off + k0 + q * 8) : zz;
            rAl[qq] = arow_ok ? *(const short8*)(const void*)(Alo + arow_off + k0 + q * 8) : zz;
        }
        #pragma unroll
        for (int c = 0; c < BCH; ++c) {
            int i = tid + c * 256;
            if (i < NT * 64) {
                int r = i >> 2;
                int q = i & 3;
                size_t boff = (size_t)r * KP + k0 + q * 8;
                rBh[c] = *(const short8*)(const void*)(Bhi + boff);
                rBl[c] = *(const short8*)(const void*)(Blo + boff);
            }
        }
    };
    auto write_lds = [&]() {
        #pragma unroll
        for (int qq = 0; qq < 2; ++qq) {
            int q = aq + qq;
            *(short8*)(void*)&AsH[ar][q * 8] = rAh[qq];
            *(short8*)(void*)&AsL[ar][q * 8] = rAl[qq];
        }
        #pragma unroll
        for (int c = 0; c < BCH; ++c) {
            int i = tid + c * 256;
            if (i < NT * 64) {
                int r = i >> 2;
                int q = i & 3;
                *(short8*)(void*)&BsH[r][q * 8] = rBh[c];
                *(short8*)(void*)&BsL[r][q * 8] = rBl[c];
            }
        }
    };

    load_regs(0);
    for (int kt = 0; kt < NK; ++kt) {
        write_lds();
        __syncthreads();
        if (kt + 1 < NK) load_regs(kt + 1);  // issue next-step loads; MFMA hides latency

        const int fr = lane & 15;
        const int fk = (lane >> 4) * 8;
        short8 ah[2], al[2];
        #pragma unroll
        for (int mt = 0; mt < 2; ++mt) {
            int r = w * 32 + mt * 16 + fr;
            ah[mt] = *(const short8*)(const void*)&AsH[r][fk];
            al[mt] = *(const short8*)(const void*)&AsL[r][fk];
        }
        #pragma unroll
        for (int nt = 0; nt < NT; ++nt) {
            int r = nt * 16 + fr;
            short8 bh = *(const short8*)(const void*)&BsH[r][fk];
            short8 bl = *(const short8*)(const void*)&BsL[r][fk];
            #pragma unroll
            for (int mt = 0; mt < 2; ++mt) {
                acc[mt][nt] = __builtin_amdgcn_mfma_f32_16x16x32_bf16(ah[mt], bh, acc[mt][nt], 0, 0, 0);
                acc[mt][nt] = __builtin_amdgcn_mfma_f32_16x16x32_bf16(ah[mt], bl, acc[mt][nt], 0, 0, 0);
                acc[mt][nt] = __builtin_amdgcn_mfma_f32_16x16x32_bf16(al[mt], bh, acc[mt][nt], 0, 0, 0);
            }
        }
        __syncthreads();
    }

    const int fr = lane & 15;
    const int fq = lane >> 4;
    #pragma unroll
    for (int mt = 0; mt < 2; ++mt)
        #pragma unroll
        for (int nt = 0; nt < NT; ++nt) {
            int col = nt * 16 + fr;
            if (col < strideC) {
                #pragma unroll
                for (int r = 0; r < 4; ++r) {
                    int row = brow + w * 32 + mt * 16 + fq * 4 + r;
                    if (row < M) C[(size_t)row * strideC + col] = acc[mt][nt][r];
                }
            }
        }
}

// ---------------------------------------------------------------------------
// Fused aggregation + bias + activation. float4 gather, 8-edge unroll.
// One wave per node, 4 nodes per 256-block. H rows padded to FP (pad = 0).
// ---------------------------------------------------------------------------
__device__ __forceinline__ float4 f4_add(float4 a, float4 b) {
    a.x += b.x; a.y += b.y; a.z += b.z; a.w += b.w;
    return a;
}

template <int ACT, int F, int FP, int KPOUT>
__global__ __launch_bounds__(256) void agg_act(const float* __restrict__ H,
                                               const int* __restrict__ row_start,
                                               const int* __restrict__ esrc,
                                               const float* __restrict__ bias,
                                               float* __restrict__ outF,
                                               ushort* __restrict__ ohi,
                                               ushort* __restrict__ olo) {
    constexpr int CPN = FP / 4;
    const int wid = threadIdx.x >> 6;
    const int lane = threadIdx.x & 63;
    const int v = blockIdx.x * 4 + wid;
    if (v >= N_NODES) return;

    const int e0 = row_start[v];
    const int e1 = row_start[v + 1];
    const bool al = lane < CPN;
    const float4* Hv = (const float4*)H;

    float4 acc = {0.f, 0.f, 0.f, 0.f};
    int e = e0;
    for (; e + 8 <= e1; e += 8) {
        int s0 = esrc[e + 0], s1 = esrc[e + 1], s2 = esrc[e + 2], s3 = esrc[e + 3];
        int s4 = esrc[e + 4], s5 = esrc[e + 5], s6 = esrc[e + 6], s7 = esrc[e + 7];
        if (al) {
            float4 v0 = Hv[(size_t)s0 * CPN + lane];
            float4 v1 = Hv[(size_t)s1 * CPN + lane];
            float4 v2 = Hv[(size_t)s2 * CPN + lane];
            float4 v3 = Hv[(size_t)s3 * CPN + lane];
            float4 v4 = Hv[(size_t)s4 * CPN + lane];
            float4 v5 = Hv[(size_t)s5 * CPN + lane];
            float4 v6 = Hv[(size_t)s6 * CPN + lane];
            float4 v7 = Hv[(size_t)s7 * CPN + lane];
            acc = f4_add(acc, f4_add(f4_add(f4_add(v0, v1), f4_add(v2, v3)),
                                     f4_add(f4_add(v4, v5), f4_add(v6, v7))));
        }
    }
    if (e + 4 <= e1) {
        int s0 = esrc[e + 0], s1 = esrc[e + 1], s2 = esrc[e + 2], s3 = esrc[e + 3];
        if (al) {
            float4 v0 = Hv[(size_t)s0 * CPN + lane];
            float4 v1 = Hv[(size_t)s1 * CPN + lane];
            float4 v2 = Hv[(size_t)s2 * CPN + lane];
            float4 v3 = Hv[(size_t)s3 * CPN + lane];
            acc = f4_add(acc, f4_add(f4_add(v0, v1), f4_add(v2, v3)));
        }
        e += 4;
    }
    for (; e < e1; ++e) {
        int s = esrc[e];
        if (al) acc = f4_add(acc, Hv[(size_t)s * CPN + lane]);
    }

    const int jb = lane * 4;
    float a[4] = {acc.x, acc.y, acc.z, acc.w};
    #pragma unroll
    for (int k = 0; k < 4; ++k) {
        int j = jb + k;
        a[k] += (al && j < F) ? bias[j] : 0.f;
    }

    float res[4] = {0.f, 0.f, 0.f, 0.f};
    if (ACT == 0) {
        #pragma unroll
        for (int k = 0; k < 4; ++k)
            res[k] = (a[k] >= 0.f) ? a[k] : 0.01f * a[k];
    } else {
        float m = -INFINITY;
        #pragma unroll
        for (int k = 0; k < 4; ++k) {
            int j = jb + k;
            if (al && j < F) m = fmaxf(m, a[k]);
        }
        #pragma unroll
        for (int off = 32; off > 0; off >>= 1) m = fmaxf(m, __shfl_xor(m, off));
        float p[4];
        float s = 0.f;
        #pragma unroll
        for (int k = 0; k < 4; ++k) {
            int j = jb + k;
            if (al && j < F) { p[k] = expf(a[k] - m); s += p[k]; } else p[k] = 0.f;
        }
        #pragma unroll
        for (int off = 32; off > 0; off >>= 1) s += __shfl_xor(s, off);
        if (ACT == 1) {
            float inv = 1.f / s;
            #pragma unroll
            for (int k = 0; k < 4; ++k) res[k] = p[k] * inv;
        } else {
            float ls = logf(s);
            #pragma unroll
            for (int k = 0; k < 4; ++k) res[k] = a[k] - m - ls;
        }
    }

    if (KPOUT == 0) {
        float* orow = outF + (size_t)v * F;
        #pragma unroll
        for (int k = 0; k < 4; ++k) {
            int j = jb + k;
            if (al && j < F) orow[j] = res[k];
        }
    } else {
        if (lane < KPOUT / 4) {
            u16x4 h4 = {0, 0, 0, 0}, l4 = {0, 0, 0, 0};
            #pragma unroll
            for (int k = 0; k < 4; ++k) {
                int j = jb + k;
                float y = (j < F) ? res[k] : 0.f;
                ushort h = bf16_rne(y);
                h4[k] = h;
                l4[k] = bf16_rne(y - bf16_to_f32(h));
            }
            size_t o = (size_t)v * KPOUT + jb;
            *(u16x4*)(void*)(ohi + o) = h4;
            *(u16x4*)(void*)(olo + o) = l4;
        }
    }
}

// ---------------------------------------------------------------------------
// Host launch
// ---------------------------------------------------------------------------
static inline size_t align_up(size_t x, size_t a) { return (x + a - 1) & ~(a - 1); }

extern "C" void kernel_launch(void* const* d_in, const int* in_sizes, int n_in,
                              void* d_out, int out_size, void* d_ws, size_t ws_size,
                              hipStream_t stream) {
    const float* features = (const float*)d_in[0];
    const int* src = (const int*)d_in[1];
    const int* dst = (const int*)d_in[2];
    const float* W[6];
    const float* b[6];
    for (int l = 0; l < 6; ++l) {
        W[l] = (const float*)d_in[3 + 2 * l];
        b[l] = (const float*)d_in[4 + 2 * l];
    }

    const int fout[6] = {200, 150, 100, 50, 25, 3};
    const int KPin[6] = {320, 224, 160, 128, 64, 32};
    const int NPl[6]  = {208, 160, 112, 64, 32, 16};   // NT*16
    const int FPl[6]  = {200, 152, 100, 52, 28, 4};    // H row stride (align4)

    // workspace layout
    char* ws = (char*)d_ws;
    size_t off = 0;
    int* row_start = (int*)(ws + off); off = align_up(off + (N_NODES + 1) * sizeof(int), 256);
    int* cursor    = (int*)(ws + off); off = align_up(off + (N_NODES + 1) * sizeof(int), 256);
    int* esrc      = (int*)(ws + off); off = align_up(off + N_EDGES * sizeof(int), 256);
    int* scan_loc  = (int*)(ws + off); off = align_up(off + N_NODES * sizeof(int), 256);
    int* blockSums = (int*)(ws + off); off = align_up(off + 64 * sizeof(int), 256);
    ushort* Wthi[6];
    ushort* Wtlo[6];
    for (int l = 0; l < 6; ++l) {
        Wthi[l] = (ushort*)(ws + off); off = align_up(off + (size_t)NPl[l] * KPin[l] * 2, 256);
        Wtlo[l] = (ushort*)(ws + off); off = align_up(off + (size_t)NPl[l] * KPin[l] * 2, 256);
    }
    ushort* Xhi = (ushort*)(ws + off); off = align_up(off + (size_t)N_NODES * 320 * 2, 256);
    ushort* Xlo = (ushort*)(ws + off); off = align_up(off + (size_t)N_NODES * 320 * 2, 256);
    float* H    = (float*)(ws + off);  off = align_up(off + (size_t)N_NODES * 200 * 4, 256);
    (void)ws_size;

    // --- build CSR by dst ---
    {
        const int nb = (N_NODES + 1023) / 1024;  // 49
        zero_int_kernel<<<(N_NODES + 255) / 256, 256, 0, stream>>>(cursor, N_NODES);
        count_kernel<<<(N_EDGES + 255) / 256, 256, 0, stream>>>(dst, cursor, N_EDGES);
        scan_p1<<<nb, 256, 0, stream>>>(cursor, scan_loc, blockSums, N_NODES);
        scan_p2<<<1, 64, 0, stream>>>(blockSums, nb);
        scan_p3<<<nb, 256, 0, stream>>>(scan_loc, blockSums, row_start, cursor, N_NODES, N_EDGES);
        fill_kernel<<<(N_EDGES + 255) / 256, 256, 0, stream>>>(src, dst, cursor, esrc, N_EDGES);
    }

    // --- weight conversion ---
    {
        WtDescs wd;
        const int fin[6] = {300, 200, 150, 100, 50, 25};
        for (int l = 0; l < 6; ++l)
            wd.d[l] = WtDesc{W[l], Wthi[l], Wtlo[l], fin[l], fout[l], KPin[l], NPl[l]};
        convert_w<<<dim3(320, 6), 256, 0, stream>>>(wd);
    }

    // --- features -> split bf16 padded (vectorized) ---
    convert_x4<<<(N_NODES * 80 + 255) / 256, 256, 0, stream>>>(features, Xhi, Xlo);

    const int gy = (N_NODES + 127) / 128;  // 391
    const int ga = (N_NODES + 3) / 4;      // 12500

    gemm_split<320, 13><<<gy, 256, 0, stream>>>(Xhi, Xlo, Wthi[0], Wtlo[0], H, N_NODES, FPl[0]);
    agg_act<0, 200, 200, 224><<<ga, 256, 0, stream>>>(H, row_start, esrc, b[0], nullptr, Xhi, Xlo);

    gemm_split<224, 10><<<gy, 256, 0, stream>>>(Xhi, Xlo, Wthi[1], Wtlo[1], H, N_NODES, FPl[1]);
    agg_act<1, 150, 152, 160><<<ga, 256, 0, stream>>>(H, row_start, esrc, b[1], nullptr, Xhi, Xlo);

    gemm_split<160, 7><<<gy, 256, 0, stream>>>(Xhi, Xlo, Wthi[2], Wtlo[2], H, N_NODES, FPl[2]);
    agg_act<0, 100, 100, 128><<<ga, 256, 0, stream>>>(H, row_start, esrc, b[2], nullptr, Xhi, Xlo);

    gemm_split<128, 4><<<gy, 256, 0, stream>>>(Xhi, Xlo, Wthi[3], Wtlo[3], H, N_NODES, FPl[3]);
    agg_act<1, 50, 52, 64><<<ga, 256, 0, stream>>>(H, row_start, esrc, b[3], nullptr, Xhi, Xlo);

    gemm_split<64, 2><<<gy, 256, 0, stream>>>(Xhi, Xlo, Wthi[4], Wtlo[4], H, N_NODES, FPl[4]);
    agg_act<0, 25, 28, 32><<<ga, 256, 0, stream>>>(H, row_start, esrc, b[4], nullptr, Xhi, Xlo);

    gemm_split<32, 1><<<gy, 256, 0, stream>>>(Xhi, Xlo, Wthi[5], Wtlo[5], H, N_NODES, FPl[5]);
    agg_act<2, 3, 4, 0><<<ga, 256, 0, stream>>>(H, row_start, esrc, b[5], (float*)d_out, nullptr, nullptr);

    (void)out_size; (void)n_in; (void)in_sizes;
}

// Round 7
// 291.046 us; speedup vs baseline: 2.6666x; 1.1756x over previous
//
#include <hip/hip_runtime.h>
#include <math.h>

#define N_NODES 50000
#define N_EDGES 262144

using short8  = __attribute__((ext_vector_type(8))) short;
using f32x4   = __attribute__((ext_vector_type(4))) float;
using u16x4   = __attribute__((ext_vector_type(4))) unsigned short;
using uint4v  = __attribute__((ext_vector_type(4))) unsigned int;

// ---------------------------------------------------------------------------
// bf16 split helpers (RNE)
// ---------------------------------------------------------------------------
__device__ __forceinline__ ushort bf16_rne(float x) {
    uint u = __float_as_uint(x);
    uint r = (u + 0x7FFFu + ((u >> 16) & 1u)) >> 16;
    return (ushort)r;
}
__device__ __forceinline__ float bf16_to_f32(ushort h) {
    return __uint_as_float(((uint)h) << 16);
}

// ---------------------------------------------------------------------------
// CSR build kernels
// ---------------------------------------------------------------------------
__global__ void zero_int_kernel(int* p, int n) {
    int i = blockIdx.x * 256 + threadIdx.x;
    if (i < n) p[i] = 0;
}

__global__ void count_kernel(const int* __restrict__ dst, int* __restrict__ deg, int E) {
    int e = blockIdx.x * 256 + threadIdx.x;
    if (e < E) atomicAdd(&deg[dst[e]], 1);
}

// --- 3-phase scan ---
__global__ __launch_bounds__(256) void scan_p1(const int* __restrict__ deg,
                                               int* __restrict__ local,
                                               int* __restrict__ blockSums, int n) {
    __shared__ int wsum[4];
    int b = blockIdx.x;
    int t = threadIdx.x;
    int i0 = b * 1024 + t * 4;
    int x0 = 0, x1 = 0, x2 = 0, x3 = 0;
    if (i0 + 3 < n) {
        int4 v = *(const int4*)(const void*)(deg + i0);
        x0 = v.x; x1 = v.y; x2 = v.z; x3 = v.w;
    } else {
        if (i0 + 0 < n) x0 = deg[i0 + 0];
        if (i0 + 1 < n) x1 = deg[i0 + 1];
        if (i0 + 2 < n) x2 = deg[i0 + 2];
        if (i0 + 3 < n) x3 = deg[i0 + 3];
    }
    int s = x0 + x1 + x2 + x3;
    int lane = t & 63;
    int wid = t >> 6;
    int incl = s;
    #pragma unroll
    for (int off = 1; off < 64; off <<= 1) {
        int u = __shfl_up(incl, off);
        if (lane >= off) incl += u;
    }
    if (lane == 63) wsum[wid] = incl;
    __syncthreads();
    int woff = 0;
    #pragma unroll
    for (int k = 0; k < 4; ++k)
        if (k < wid) woff += wsum[k];
    int texcl = woff + incl - s;
    if (i0 + 3 < n) {
        int4 o;
        o.x = texcl;
        o.y = texcl + x0;
        o.z = texcl + x0 + x1;
        o.w = texcl + x0 + x1 + x2;
        *(int4*)(void*)(local + i0) = o;
    } else {
        if (i0 + 0 < n) local[i0 + 0] = texcl;
        if (i0 + 1 < n) local[i0 + 1] = texcl + x0;
        if (i0 + 2 < n) local[i0 + 2] = texcl + x0 + x1;
        if (i0 + 3 < n) local[i0 + 3] = texcl + x0 + x1 + x2;
    }
    if (t == 0) blockSums[b] = wsum[0] + wsum[1] + wsum[2] + wsum[3];
}

__global__ __launch_bounds__(64) void scan_p2(int* __restrict__ blockSums, int nb) {
    int lane = threadIdx.x;
    int s = (lane < nb) ? blockSums[lane] : 0;
    int incl = s;
    #pragma unroll
    for (int off = 1; off < 64; off <<= 1) {
        int u = __shfl_up(incl, off);
        if (lane >= off) incl += u;
    }
    if (lane < nb) blockSums[lane] = incl - s;
}

__global__ __launch_bounds__(256) void scan_p3(const int* __restrict__ local,
                                               const int* __restrict__ blockSums,
                                               int* __restrict__ row_start,
                                               int* __restrict__ cursor, int n, int total) {
    int b = blockIdx.x;
    int off = blockSums[b];
    int i0 = b * 1024 + threadIdx.x * 4;
    if (i0 + 3 < n) {
        int4 v = *(const int4*)(const void*)(local + i0);
        v.x += off; v.y += off; v.z += off; v.w += off;
        *(int4*)(void*)(row_start + i0) = v;
        *(int4*)(void*)(cursor + i0) = v;
    } else {
        #pragma unroll
        for (int k = 0; k < 4; ++k)
            if (i0 + k < n) {
                int v = local[i0 + k] + off;
                row_start[i0 + k] = v;
                cursor[i0 + k] = v;
            }
    }
    if (b == 0 && threadIdx.x == 0) row_start[n] = total;
}

__global__ void fill_kernel(const int* __restrict__ src, const int* __restrict__ dst,
                            int* __restrict__ cursor, int* __restrict__ esrc, int E) {
    int e = blockIdx.x * 256 + threadIdx.x;
    if (e < E) {
        int d = dst[e];
        int pos = atomicAdd(&cursor[d], 1);
        esrc[pos] = src[e];
    }
}

// ---------------------------------------------------------------------------
// features f32 [N][300] -> split-bf16 [N][320], float4/ushort4 vectorized
// ---------------------------------------------------------------------------
__global__ void convert_x4(const float* __restrict__ X, ushort* __restrict__ hi,
                           ushort* __restrict__ lo) {
    int idx = blockIdx.x * 256 + threadIdx.x;
    if (idx >= N_NODES * 80) return;
    int row = idx / 80;
    int c = idx - row * 80;
    u16x4 h4 = {0, 0, 0, 0}, l4 = {0, 0, 0, 0};
    if (c < 75) {
        float4 v = *(const float4*)(const void*)(X + (size_t)row * 300 + c * 4);
        float vv[4] = {v.x, v.y, v.z, v.w};
        #pragma unroll
        for (int k = 0; k < 4; ++k) {
            ushort h = bf16_rne(vv[k]);
            h4[k] = h;
            l4[k] = bf16_rne(vv[k] - bf16_to_f32(h));
        }
    }
    size_t o = (size_t)row * 320 + c * 4;
    *(u16x4*)(void*)(hi + o) = h4;
    *(u16x4*)(void*)(lo + o) = l4;
}

struct WtDesc { const float* W; ushort* hi; ushort* lo; int K, N, KP, NP; };
struct WtDescs { WtDesc d[6]; };

__global__ void convert_w(WtDescs all) {
    WtDesc d = all.d[blockIdx.y];
    int total = d.NP * d.KP;
    for (int idx = blockIdx.x * 256 + threadIdx.x; idx < total; idx += gridDim.x * 256) {
        int n = idx / d.KP;
        int k = idx - n * d.KP;
        float v = (n < d.N && k < d.K) ? d.W[(size_t)k * d.N + n] : 0.f;
        ushort h = bf16_rne(v);
        d.hi[idx] = h;
        d.lo[idx] = bf16_rne(v - bf16_to_f32(h));
    }
}

// ---------------------------------------------------------------------------
// Split-bf16 MFMA GEMM, full-N per block, register-prefetch pipeline.
// Output H is written as bf16 (RNE), row stride FP (pad cols exact 0).
// ---------------------------------------------------------------------------
template <int KP, int NT>
__global__ __launch_bounds__(256) void gemm_split(const ushort* __restrict__ Ahi,
                                                  const ushort* __restrict__ Alo,
                                                  const ushort* __restrict__ Bhi,
                                                  const ushort* __restrict__ Blo,
                                                  ushort* __restrict__ Hb, int M, int FP) {
    __shared__ __align__(16) ushort AsH[128][40];
    __shared__ __align__(16) ushort AsL[128][40];
    __shared__ __align__(16) ushort BsH[NT * 16][40];
    __shared__ __align__(16) ushort BsL[NT * 16][40];

    constexpr int NK = KP / 32;
    constexpr int BCH = (NT * 64 + 255) / 256;

    const int tid = threadIdx.x;
    const int lane = tid & 63;
    const int w = tid >> 6;
    const int brow = blockIdx.x * 128;

    f32x4 acc[2][NT];
    #pragma unroll
    for (int mt = 0; mt < 2; ++mt)
        #pragma unroll
        for (int nt = 0; nt < NT; ++nt)
            acc[mt][nt] = (f32x4){0.f, 0.f, 0.f, 0.f};

    const int ar = tid >> 1;
    const int aq = (tid & 1) * 2;
    const bool arow_ok = (brow + ar) < M;
    const size_t arow_off = (size_t)(brow + ar) * KP;

    const short8 zz = {0, 0, 0, 0, 0, 0, 0, 0};

    short8 rAh[2], rAl[2], rBh[BCH], rBl[BCH];

    auto load_regs = [&](int kt) {
        const int k0 = kt * 32;
        #pragma unroll
        for (int qq = 0; qq < 2; ++qq) {
            int q = aq + qq;
            rAh[qq] = arow_ok ? *(const short8*)(const void*)(Ahi + arow_off + k0 + q * 8) : zz;
            rAl[qq] = arow_ok ? *(const short8*)(const void*)(Alo + arow_off + k0 + q * 8) : zz;
        }
        #pragma unroll
        for (int c = 0; c < BCH; ++c) {
            int i = tid + c * 256;
            if (i < NT * 64) {
                int r = i >> 2;
                int q = i & 3;
                size_t boff = (size_t)r * KP + k0 + q * 8;
                rBh[c] = *(const short8*)(const void*)(Bhi + boff);
                rBl[c] = *(const short8*)(const void*)(Blo + boff);
            }
        }
    };
    auto write_lds = [&]() {
        #pragma unroll
        for (int qq = 0; qq < 2; ++qq) {
            int q = aq + qq;
            *(short8*)(void*)&AsH[ar][q * 8] = rAh[qq];
            *(short8*)(void*)&AsL[ar][q * 8] = rAl[qq];
        }
        #pragma unroll
        for (int c = 0; c < BCH; ++c) {
            int i = tid + c * 256;
            if (i < NT * 64) {
                int r = i >> 2;
                int q = i & 3;
                *(short8*)(void*)&BsH[r][q * 8] = rBh[c];
                *(short8*)(void*)&BsL[r][q * 8] = rBl[c];
            }
        }
    };

    load_regs(0);
    for (int kt = 0; kt < NK; ++kt) {
        write_lds();
        __syncthreads();
        if (kt + 1 < NK) load_regs(kt + 1);

        const int fr = lane & 15;
        const int fk = (lane >> 4) * 8;
        short8 ah[2], al[2];
        #pragma unroll
        for (int mt = 0; mt < 2; ++mt) {
            int r = w * 32 + mt * 16 + fr;
            ah[mt] = *(const short8*)(const void*)&AsH[r][fk];
            al[mt] = *(const short8*)(const void*)&AsL[r][fk];
        }
        #pragma unroll
        for (int nt = 0; nt < NT; ++nt) {
            int r = nt * 16 + fr;
            short8 bh = *(const short8*)(const void*)&BsH[r][fk];
            short8 bl = *(const short8*)(const void*)&BsL[r][fk];
            #pragma unroll
            for (int mt = 0; mt < 2; ++mt) {
                acc[mt][nt] = __builtin_amdgcn_mfma_f32_16x16x32_bf16(ah[mt], bh, acc[mt][nt], 0, 0, 0);
                acc[mt][nt] = __builtin_amdgcn_mfma_f32_16x16x32_bf16(ah[mt], bl, acc[mt][nt], 0, 0, 0);
                acc[mt][nt] = __builtin_amdgcn_mfma_f32_16x16x32_bf16(al[mt], bh, acc[mt][nt], 0, 0, 0);
            }
        }
        __syncthreads();
    }

    const int fr = lane & 15;
    const int fq = lane >> 4;
    #pragma unroll
    for (int mt = 0; mt < 2; ++mt)
        #pragma unroll
        for (int nt = 0; nt < NT; ++nt) {
            int col = nt * 16 + fr;
            if (col < FP) {
                #pragma unroll
                for (int r = 0; r < 4; ++r) {
                    int row = brow + w * 32 + mt * 16 + fq * 4 + r;
                    if (row < M) Hb[(size_t)row * FP + col] = bf16_rne(acc[mt][nt][r]);
                }
            }
        }
}

// ---------------------------------------------------------------------------
// Fused aggregation + bias + activation, bf16 H gather, sub-wave per node.
// SW lanes per node (power of 2); each lane owns 8 features (one ushort8).
// ACT: 0 leaky, 1 softmax, 2 log_softmax.
// ---------------------------------------------------------------------------
template <int ACT, int F, int FP, int KPOUT, int SW>
__global__ __launch_bounds__(256) void agg_act(const ushort* __restrict__ Hb,
                                               const int* __restrict__ row_start,
                                               const int* __restrict__ esrc,
                                               const float* __restrict__ bias,
                                               float* __restrict__ outF,
                                               ushort* __restrict__ ohi,
                                               ushort* __restrict__ olo) {
    constexpr int CH = FP / 8;       // ushort8 chunks per H row
    constexpr int NPB = 256 / SW;    // nodes per block
    static_assert(CH <= SW, "chunks must fit sub-wave");

    const int t = threadIdx.x;
    const int sub = t / SW;
    const int subl = t - sub * SW;
    const int v = blockIdx.x * NPB + sub;
    if (v >= N_NODES) return;

    const int e0 = row_start[v];
    const int e1 = row_start[v + 1];
    const bool al = subl < CH;
    const uint4v* Hc = (const uint4v*)Hb;  // 16B chunk view; row = CH chunks

    float a[8] = {0.f, 0.f, 0.f, 0.f, 0.f, 0.f, 0.f, 0.f};

    #define ACCUM(rr)                                            \
        {                                                        \
            _Pragma("unroll")                                    \
            for (int k = 0; k < 4; ++k) {                        \
                uint u = (rr)[k];                                \
                a[2 * k]     += __uint_as_float(u << 16);        \
                a[2 * k + 1] += __uint_as_float(u & 0xFFFF0000u);\
            }                                                    \
        }

    int e = e0;
    for (; e + 8 <= e1; e += 8) {
        int s0 = esrc[e + 0], s1 = esrc[e + 1], s2 = esrc[e + 2], s3 = esrc[e + 3];
        int s4 = esrc[e + 4], s5 = esrc[e + 5], s6 = esrc[e + 6], s7 = esrc[e + 7];
        if (al) {
            uint4v r0 = Hc[(size_t)s0 * CH + subl];
            uint4v r1 = Hc[(size_t)s1 * CH + subl];
            uint4v r2 = Hc[(size_t)s2 * CH + subl];
            uint4v r3 = Hc[(size_t)s3 * CH + subl];
            uint4v r4 = Hc[(size_t)s4 * CH + subl];
            uint4v r5 = Hc[(size_t)s5 * CH + subl];
            uint4v r6 = Hc[(size_t)s6 * CH + subl];
            uint4v r7 = Hc[(size_t)s7 * CH + subl];
            ACCUM(r0) ACCUM(r1) ACCUM(r2) ACCUM(r3)
            ACCUM(r4) ACCUM(r5) ACCUM(r6) ACCUM(r7)
        }
    }
    if (e + 4 <= e1) {
        int s0 = esrc[e + 0], s1 = esrc[e + 1], s2 = esrc[e + 2], s3 = esrc[e + 3];
        if (al) {
            uint4v r0 = Hc[(size_t)s0 * CH + subl];
            uint4v r1 = Hc[(size_t)s1 * CH + subl];
            uint4v r2 = Hc[(size_t)s2 * CH + subl];
            uint4v r3 = Hc[(size_t)s3 * CH + subl];
            ACCUM(r0) ACCUM(r1) ACCUM(r2) ACCUM(r3)
        }
        e += 4;
    }
    for (; e < e1; ++e) {
        int s = esrc[e];
        if (al) {
            uint4v r = Hc[(size_t)s * CH + subl];
            ACCUM(r)
        }
    }
    #undef ACCUM

    const int jb = subl * 8;
    #pragma unroll
    for (int k = 0; k < 8; ++k) {
        int j = jb + k;
        a[k] += (al && j < F) ? bias[j] : 0.f;
    }

    float res[8];
    if (ACT == 0) {
        #pragma unroll
        for (int k = 0; k < 8; ++k)
            res[k] = (a[k] >= 0.f) ? a[k] : 0.01f * a[k];
    } else {
        float m = -INFINITY;
        #pragma unroll
        for (int k = 0; k < 8; ++k) {
            int j = jb + k;
            if (al && j < F) m = fmaxf(m, a[k]);
        }
        if (SW > 1) {
            #pragma unroll
            for (int off = SW / 2; off > 0; off >>= 1) m = fmaxf(m, __shfl_xor(m, off));
        }
        float p[8];
        float s = 0.f;
        #pragma unroll
        for (int k = 0; k < 8; ++k) {
            int j = jb + k;
            if (al && j < F) { p[k] = expf(a[k] - m); s += p[k]; } else p[k] = 0.f;
        }
        if (SW > 1) {
            #pragma unroll
            for (int off = SW / 2; off > 0; off >>= 1) s += __shfl_xor(s, off);
        }
        if (ACT == 1) {
            float inv = 1.f / s;
            #pragma unroll
            for (int k = 0; k < 8; ++k) res[k] = p[k] * inv;
        } else {
            float ls = logf(s);
            #pragma unroll
            for (int k = 0; k < 8; ++k) res[k] = a[k] - m - ls;
        }
    }

    if (KPOUT == 0) {
        float* orow = outF + (size_t)v * F;
        #pragma unroll
        for (int k = 0; k < 8; ++k) {
            int j = jb + k;
            if (al && j < F) orow[j] = res[k];
        }
    } else {
        if (jb < KPOUT) {
            u16x4 h4a = {0, 0, 0, 0}, l4a = {0, 0, 0, 0};
            u16x4 h4b = {0, 0, 0, 0}, l4b = {0, 0, 0, 0};
            #pragma unroll
            for (int k = 0; k < 4; ++k) {
                int j = jb + k;
                float y = (j < F) ? res[k] : 0.f;
                ushort h = bf16_rne(y);
                h4a[k] = h;
                l4a[k] = bf16_rne(y - bf16_to_f32(h));
            }
            #pragma unroll
            for (int k = 0; k < 4; ++k) {
                int j = jb + 4 + k;
                float y = (j < F) ? res[4 + k] : 0.f;
                ushort h = bf16_rne(y);
                h4b[k] = h;
                l4b[k] = bf16_rne(y - bf16_to_f32(h));
            }
            size_t o = (size_t)v * KPOUT + jb;
            *(u16x4*)(void*)(ohi + o) = h4a;
            *(u16x4*)(void*)(ohi + o + 4) = h4b;
            *(u16x4*)(void*)(olo + o) = l4a;
            *(u16x4*)(void*)(olo + o + 4) = l4b;
        }
    }
}

// ---------------------------------------------------------------------------
// Host launch
// ---------------------------------------------------------------------------
static inline size_t align_up(size_t x, size_t a) { return (x + a - 1) & ~(a - 1); }

extern "C" void kernel_launch(void* const* d_in, const int* in_sizes, int n_in,
                              void* d_out, int out_size, void* d_ws, size_t ws_size,
                              hipStream_t stream) {
    const float* features = (const float*)d_in[0];
    const int* src = (const int*)d_in[1];
    const int* dst = (const int*)d_in[2];
    const float* W[6];
    const float* b[6];
    for (int l = 0; l < 6; ++l) {
        W[l] = (const float*)d_in[3 + 2 * l];
        b[l] = (const float*)d_in[4 + 2 * l];
    }

    const int fout[6] = {200, 150, 100, 50, 25, 3};
    const int KPin[6] = {320, 224, 160, 128, 64, 32};
    const int NPl[6]  = {208, 160, 112, 64, 32, 16};   // NT*16
    const int FPl[6]  = {200, 152, 104, 56, 32, 8};    // bf16 H row stride (mult of 8)

    // workspace layout
    char* ws = (char*)d_ws;
    size_t off = 0;
    int* row_start = (int*)(ws + off); off = align_up(off + (N_NODES + 1) * sizeof(int), 256);
    int* cursor    = (int*)(ws + off); off = align_up(off + (N_NODES + 1) * sizeof(int), 256);
    int* esrc      = (int*)(ws + off); off = align_up(off + N_EDGES * sizeof(int), 256);
    int* scan_loc  = (int*)(ws + off); off = align_up(off + N_NODES * sizeof(int), 256);
    int* blockSums = (int*)(ws + off); off = align_up(off + 64 * sizeof(int), 256);
    ushort* Wthi[6];
    ushort* Wtlo[6];
    for (int l = 0; l < 6; ++l) {
        Wthi[l] = (ushort*)(ws + off); off = align_up(off + (size_t)NPl[l] * KPin[l] * 2, 256);
        Wtlo[l] = (ushort*)(ws + off); off = align_up(off + (size_t)NPl[l] * KPin[l] * 2, 256);
    }
    ushort* Xhi = (ushort*)(ws + off); off = align_up(off + (size_t)N_NODES * 320 * 2, 256);
    ushort* Xlo = (ushort*)(ws + off); off = align_up(off + (size_t)N_NODES * 320 * 2, 256);
    ushort* Hb  = (ushort*)(ws + off); off = align_up(off + (size_t)N_NODES * 200 * 2, 256);
    (void)ws_size;

    // --- build CSR by dst ---
    {
        const int nb = (N_NODES + 1023) / 1024;  // 49
        zero_int_kernel<<<(N_NODES + 255) / 256, 256, 0, stream>>>(cursor, N_NODES);
        count_kernel<<<(N_EDGES + 255) / 256, 256, 0, stream>>>(dst, cursor, N_EDGES);
        scan_p1<<<nb, 256, 0, stream>>>(cursor, scan_loc, blockSums, N_NODES);
        scan_p2<<<1, 64, 0, stream>>>(blockSums, nb);
        scan_p3<<<nb, 256, 0, stream>>>(scan_loc, blockSums, row_start, cursor, N_NODES, N_EDGES);
        fill_kernel<<<(N_EDGES + 255) / 256, 256, 0, stream>>>(src, dst, cursor, esrc, N_EDGES);
    }

    // --- weight conversion ---
    {
        WtDescs wd;
        const int fin[6] = {300, 200, 150, 100, 50, 25};
        for (int l = 0; l < 6; ++l)
            wd.d[l] = WtDesc{W[l], Wthi[l], Wtlo[l], fin[l], fout[l], KPin[l], NPl[l]};
        convert_w<<<dim3(320, 6), 256, 0, stream>>>(wd);
    }

    // --- features -> split bf16 padded (vectorized) ---
    convert_x4<<<(N_NODES * 80 + 255) / 256, 256, 0, stream>>>(features, Xhi, Xlo);

    const int gy = (N_NODES + 127) / 128;  // 391

    // L1: SW=32 (CH=25), NPB=8
    gemm_split<320, 13><<<gy, 256, 0, stream>>>(Xhi, Xlo, Wthi[0], Wtlo[0], Hb, N_NODES, FPl[0]);
    agg_act<0, 200, 200, 224, 32><<<(N_NODES + 7) / 8, 256, 0, stream>>>(Hb, row_start, esrc, b[0], nullptr, Xhi, Xlo);

    // L2: SW=32 (CH=19), NPB=8
    gemm_split<224, 10><<<gy, 256, 0, stream>>>(Xhi, Xlo, Wthi[1], Wtlo[1], Hb, N_NODES, FPl[1]);
    agg_act<1, 150, 152, 160, 32><<<(N_NODES + 7) / 8, 256, 0, stream>>>(Hb, row_start, esrc, b[1], nullptr, Xhi, Xlo);

    // L3: SW=16 (CH=13), NPB=16
    gemm_split<160, 7><<<gy, 256, 0, stream>>>(Xhi, Xlo, Wthi[2], Wtlo[2], Hb, N_NODES, FPl[2]);
    agg_act<0, 100, 104, 128, 16><<<(N_NODES + 15) / 16, 256, 0, stream>>>(Hb, row_start, esrc, b[2], nullptr, Xhi, Xlo);

    // L4: SW=8 (CH=7), NPB=32
    gemm_split<128, 4><<<gy, 256, 0, stream>>>(Xhi, Xlo, Wthi[3], Wtlo[3], Hb, N_NODES, FPl[3]);
    agg_act<1, 50, 56, 64, 8><<<(N_NODES + 31) / 32, 256, 0, stream>>>(Hb, row_start, esrc, b[3], nullptr, Xhi, Xlo);

    // L5: SW=4 (CH=4), NPB=64
    gemm_split<64, 2><<<gy, 256, 0, stream>>>(Xhi, Xlo, Wthi[4], Wtlo[4], Hb, N_NODES, FPl[4]);
    agg_act<0, 25, 32, 32, 4><<<(N_NODES + 63) / 64, 256, 0, stream>>>(Hb, row_start, esrc, b[4], nullptr, Xhi, Xlo);

    // L6: SW=1 (CH=1), NPB=256
    gemm_split<32, 1><<<gy, 256, 0, stream>>>(Xhi, Xlo, Wthi[5], Wtlo[5], Hb, N_NODES, FPl[5]);
    agg_act<2, 3, 8, 0, 1><<<(N_NODES + 255) / 256, 256, 0, stream>>>(Hb, row_start, esrc, b[5], (float*)d_out, nullptr, nullptr);

    (void)out_size; (void)n_in; (void)in_sizes;
}

// Round 8
// 261.475 us; speedup vs baseline: 2.9682x; 1.1131x over previous
//
#include <hip/hip_runtime.h>
#include <math.h>

#define N_NODES 50000
#define N_EDGES 262144

using short8  = __attribute__((ext_vector_type(8))) short;
using f32x4   = __attribute__((ext_vector_type(4))) float;
using u16x4   = __attribute__((ext_vector_type(4))) unsigned short;
using uint4v  = __attribute__((ext_vector_type(4))) unsigned int;

// ---------------------------------------------------------------------------
// bf16 split helpers (RNE)
// ---------------------------------------------------------------------------
__device__ __forceinline__ ushort bf16_rne(float x) {
    uint u = __float_as_uint(x);
    uint r = (u + 0x7FFFu + ((u >> 16) & 1u)) >> 16;
    return (ushort)r;
}
__device__ __forceinline__ float bf16_to_f32(ushort h) {
    return __uint_as_float(((uint)h) << 16);
}

struct WtDesc { const float* W; ushort* hi; ushort* lo; int K, N, KP, NP; };
struct WtDescs { WtDesc d[6]; };

// ---------------------------------------------------------------------------
// Fused setup: zero cursor+blockState | convert W (all 6) | convert features
// blocks [0,196): zero; [196,2116): convert_w; [2116,17741): convert_x
// ---------------------------------------------------------------------------
__global__ __launch_bounds__(256) void setup_fused(int* __restrict__ cursor,
                                                   int* __restrict__ blockState,
                                                   WtDescs all,
                                                   const float* __restrict__ X,
                                                   ushort* __restrict__ hi,
                                                   ushort* __restrict__ lo) {
    const int b = blockIdx.x;
    const int t = threadIdx.x;
    if (b < 196) {
        int i = b * 256 + t;
        if (i < N_NODES) cursor[i] = 0;
        if (b == 0 && t < 64) blockState[t] = 0;
    } else if (b < 2116) {
        int bb = b - 196;
        WtDesc d = all.d[bb / 320];
        int total = d.NP * d.KP;
        for (int idx = (bb % 320) * 256 + t; idx < total; idx += 320 * 256) {
            int n = idx / d.KP;
            int k = idx - n * d.KP;
            float v = (n < d.N && k < d.K) ? d.W[(size_t)k * d.N + n] : 0.f;
            ushort h = bf16_rne(v);
            d.hi[idx] = h;
            d.lo[idx] = bf16_rne(v - bf16_to_f32(h));
        }
    } else {
        int idx = (b - 2116) * 256 + t;
        if (idx >= N_NODES * 80) return;
        int row = idx / 80;
        int c = idx - row * 80;
        u16x4 h4 = {0, 0, 0, 0}, l4 = {0, 0, 0, 0};
        if (c < 75) {
            float4 v = *(const float4*)(const void*)(X + (size_t)row * 300 + c * 4);
            float vv[4] = {v.x, v.y, v.z, v.w};
            #pragma unroll
            for (int k = 0; k < 4; ++k) {
                ushort h = bf16_rne(vv[k]);
                h4[k] = h;
                l4[k] = bf16_rne(vv[k] - bf16_to_f32(h));
            }
        }
        size_t o = (size_t)row * 320 + c * 4;
        *(u16x4*)(void*)(hi + o) = h4;
        *(u16x4*)(void*)(lo + o) = l4;
    }
}

// ---------------------------------------------------------------------------
// CSR build
// ---------------------------------------------------------------------------
__global__ void count_kernel(const int* __restrict__ dst, int* __restrict__ deg, int E) {
    int e = blockIdx.x * 256 + threadIdx.x;
    if (e < E) atomicAdd(&deg[dst[e]], 1);
}

// single-kernel decoupled-lookback exclusive scan (49 blocks x 1024 elems).
// blockState[b] = (value<<2) | flag; flag 1 = aggregate, 2 = inclusive prefix.
__global__ __launch_bounds__(256) void scan_lookback(const int* __restrict__ deg,
                                                     int* __restrict__ row_start,
                                                     int* __restrict__ cursor,
                                                     int* __restrict__ blockState,
                                                     int n, int total) {
    __shared__ int wsum[4];
    __shared__ int s_off;
    const int b = blockIdx.x;
    const int t = threadIdx.x;
    const int i0 = b * 1024 + t * 4;
    int x0 = 0, x1 = 0, x2 = 0, x3 = 0;
    if (i0 + 3 < n) {
        int4 v = *(const int4*)(const void*)(deg + i0);
        x0 = v.x; x1 = v.y; x2 = v.z; x3 = v.w;
    } else {
        if (i0 + 0 < n) x0 = deg[i0 + 0];
        if (i0 + 1 < n) x1 = deg[i0 + 1];
        if (i0 + 2 < n) x2 = deg[i0 + 2];
        if (i0 + 3 < n) x3 = deg[i0 + 3];
    }
    int s = x0 + x1 + x2 + x3;
    int lane = t & 63;
    int wid = t >> 6;
    int incl = s;
    #pragma unroll
    for (int off = 1; off < 64; off <<= 1) {
        int u = __shfl_up(incl, off);
        if (lane >= off) incl += u;
    }
    if (lane == 63) wsum[wid] = incl;
    __syncthreads();
    int woff = 0;
    #pragma unroll
    for (int k = 0; k < 4; ++k)
        if (k < wid) woff += wsum[k];
    int texcl = woff + incl - s;

    if (t == 0) {
        int bs = wsum[0] + wsum[1] + wsum[2] + wsum[3];
        atomicExch(&blockState[b], (bs << 2) | 1);
        int off = 0;
        for (int pb = b - 1; pb >= 0; --pb) {
            int st;
            do { st = atomicAdd(&blockState[pb], 0); } while ((st & 3) == 0);
            off += (st >> 2);
            if ((st & 3) == 2) break;
        }
        atomicExch(&blockState[b], ((off + bs) << 2) | 2);
        s_off = off;
    }
    __syncthreads();
    int off = s_off;

    if (i0 + 3 < n) {
        int4 o;
        o.x = off + texcl;
        o.y = off + texcl + x0;
        o.z = off + texcl + x0 + x1;
        o.w = off + texcl + x0 + x1 + x2;
        *(int4*)(void*)(row_start + i0) = o;
        *(int4*)(void*)(cursor + i0) = o;
    } else {
        int vals[4] = {off + texcl, off + texcl + x0, off + texcl + x0 + x1,
                       off + texcl + x0 + x1 + x2};
        #pragma unroll
        for (int k = 0; k < 4; ++k)
            if (i0 + k < n) { row_start[i0 + k] = vals[k]; cursor[i0 + k] = vals[k]; }
    }
    if (b == 0 && t == 0) row_start[n] = total;
}

__global__ void fill_kernel(const int* __restrict__ src, const int* __restrict__ dst,
                            int* __restrict__ cursor, int* __restrict__ esrc, int E) {
    int e = blockIdx.x * 256 + threadIdx.x;
    if (e < E) {
        int d = dst[e];
        int pos = atomicAdd(&cursor[d], 1);
        esrc[pos] = src[e];
    }
}

// ---------------------------------------------------------------------------
// 3-term split-bf16 MFMA GEMM (layer 1 only). H out bf16, stride FP.
// ---------------------------------------------------------------------------
template <int KP, int NT>
__global__ __launch_bounds__(256) void gemm_split(const ushort* __restrict__ Ahi,
                                                  const ushort* __restrict__ Alo,
                                                  const ushort* __restrict__ Bhi,
                                                  const ushort* __restrict__ Blo,
                                                  ushort* __restrict__ Hb, int M, int FP) {
    __shared__ __align__(16) ushort AsH[128][40];
    __shared__ __align__(16) ushort AsL[128][40];
    __shared__ __align__(16) ushort BsH[NT * 16][40];
    __shared__ __align__(16) ushort BsL[NT * 16][40];

    constexpr int NK = KP / 32;
    constexpr int BCH = (NT * 64 + 255) / 256;

    const int tid = threadIdx.x;
    const int lane = tid & 63;
    const int w = tid >> 6;
    const int brow = blockIdx.x * 128;

    f32x4 acc[2][NT];
    #pragma unroll
    for (int mt = 0; mt < 2; ++mt)
        #pragma unroll
        for (int nt = 0; nt < NT; ++nt)
            acc[mt][nt] = (f32x4){0.f, 0.f, 0.f, 0.f};

    const int ar = tid >> 1;
    const int aq = (tid & 1) * 2;
    const bool arow_ok = (brow + ar) < M;
    const size_t arow_off = (size_t)(brow + ar) * KP;

    const short8 zz = {0, 0, 0, 0, 0, 0, 0, 0};
    short8 rAh[2], rAl[2], rBh[BCH], rBl[BCH];

    auto load_regs = [&](int kt) {
        const int k0 = kt * 32;
        #pragma unroll
        for (int qq = 0; qq < 2; ++qq) {
            int q = aq + qq;
            rAh[qq] = arow_ok ? *(const short8*)(const void*)(Ahi + arow_off + k0 + q * 8) : zz;
            rAl[qq] = arow_ok ? *(const short8*)(const void*)(Alo + arow_off + k0 + q * 8) : zz;
        }
        #pragma unroll
        for (int c = 0; c < BCH; ++c) {
            int i = tid + c * 256;
            if (i < NT * 64) {
                int r = i >> 2;
                int q = i & 3;
                size_t boff = (size_t)r * KP + k0 + q * 8;
                rBh[c] = *(const short8*)(const void*)(Bhi + boff);
                rBl[c] = *(const short8*)(const void*)(Blo + boff);
            }
        }
    };
    auto write_lds = [&]() {
        #pragma unroll
        for (int qq = 0; qq < 2; ++qq) {
            int q = aq + qq;
            *(short8*)(void*)&AsH[ar][q * 8] = rAh[qq];
            *(short8*)(void*)&AsL[ar][q * 8] = rAl[qq];
        }
        #pragma unroll
        for (int c = 0; c < BCH; ++c) {
            int i = tid + c * 256;
            if (i < NT * 64) {
                int r = i >> 2;
                int q = i & 3;
                *(short8*)(void*)&BsH[r][q * 8] = rBh[c];
                *(short8*)(void*)&BsL[r][q * 8] = rBl[c];
            }
        }
    };

    load_regs(0);
    for (int kt = 0; kt < NK; ++kt) {
        write_lds();
        __syncthreads();
        if (kt + 1 < NK) load_regs(kt + 1);

        const int fr = lane & 15;
        const int fk = (lane >> 4) * 8;
        short8 ah[2], al[2];
        #pragma unroll
        for (int mt = 0; mt < 2; ++mt) {
            int r = w * 32 + mt * 16 + fr;
            ah[mt] = *(const short8*)(const void*)&AsH[r][fk];
            al[mt] = *(const short8*)(const void*)&AsL[r][fk];
        }
        #pragma unroll
        for (int nt = 0; nt < NT; ++nt) {
            int r = nt * 16 + fr;
            short8 bh = *(const short8*)(const void*)&BsH[r][fk];
            short8 bl = *(const short8*)(const void*)&BsL[r][fk];
            #pragma unroll
            for (int mt = 0; mt < 2; ++mt) {
                acc[mt][nt] = __builtin_amdgcn_mfma_f32_16x16x32_bf16(ah[mt], bh, acc[mt][nt], 0, 0, 0);
                acc[mt][nt] = __builtin_amdgcn_mfma_f32_16x16x32_bf16(ah[mt], bl, acc[mt][nt], 0, 0, 0);
                acc[mt][nt] = __builtin_amdgcn_mfma_f32_16x16x32_bf16(al[mt], bh, acc[mt][nt], 0, 0, 0);
            }
        }
        __syncthreads();
    }

    const int fr = lane & 15;
    const int fq = lane >> 4;
    #pragma unroll
    for (int mt = 0; mt < 2; ++mt)
        #pragma unroll
        for (int nt = 0; nt < NT; ++nt) {
            int col = nt * 16 + fr;
            if (col < FP) {
                #pragma unroll
                for (int r = 0; r < 4; ++r) {
                    int row = brow + w * 32 + mt * 16 + fq * 4 + r;
                    if (row < M) Hb[(size_t)row * FP + col] = bf16_rne(acc[mt][nt][r]);
                }
            }
        }
}

// ---------------------------------------------------------------------------
// 1-term bf16 MFMA GEMM (layers 2-6). H out bf16, stride FP.
// ---------------------------------------------------------------------------
template <int KP, int NT>
__global__ __launch_bounds__(256) void gemm_bf16(const ushort* __restrict__ Ahi,
                                                 const ushort* __restrict__ Bhi,
                                                 ushort* __restrict__ Hb, int M, int FP) {
    __shared__ __align__(16) ushort AsH[128][40];
    __shared__ __align__(16) ushort BsH[NT * 16][40];

    constexpr int NK = KP / 32;
    constexpr int BCH = (NT * 64 + 255) / 256;

    const int tid = threadIdx.x;
    const int lane = tid & 63;
    const int w = tid >> 6;
    const int brow = blockIdx.x * 128;

    f32x4 acc[2][NT];
    #pragma unroll
    for (int mt = 0; mt < 2; ++mt)
        #pragma unroll
        for (int nt = 0; nt < NT; ++nt)
            acc[mt][nt] = (f32x4){0.f, 0.f, 0.f, 0.f};

    const int ar = tid >> 1;
    const int aq = (tid & 1) * 2;
    const bool arow_ok = (brow + ar) < M;
    const size_t arow_off = (size_t)(brow + ar) * KP;

    const short8 zz = {0, 0, 0, 0, 0, 0, 0, 0};
    short8 rAh[2], rBh[BCH];

    auto load_regs = [&](int kt) {
        const int k0 = kt * 32;
        #pragma unroll
        for (int qq = 0; qq < 2; ++qq) {
            int q = aq + qq;
            rAh[qq] = arow_ok ? *(const short8*)(const void*)(Ahi + arow_off + k0 + q * 8) : zz;
        }
        #pragma unroll
        for (int c = 0; c < BCH; ++c) {
            int i = tid + c * 256;
            if (i < NT * 64) {
                int r = i >> 2;
                int q = i & 3;
                rBh[c] = *(const short8*)(const void*)(Bhi + (size_t)r * KP + k0 + q * 8);
            }
        }
    };
    auto write_lds = [&]() {
        #pragma unroll
        for (int qq = 0; qq < 2; ++qq) {
            int q = aq + qq;
            *(short8*)(void*)&AsH[ar][q * 8] = rAh[qq];
        }
        #pragma unroll
        for (int c = 0; c < BCH; ++c) {
            int i = tid + c * 256;
            if (i < NT * 64) {
                int r = i >> 2;
                int q = i & 3;
                *(short8*)(void*)&BsH[r][q * 8] = rBh[c];
            }
        }
    };

    load_regs(0);
    for (int kt = 0; kt < NK; ++kt) {
        write_lds();
        __syncthreads();
        if (kt + 1 < NK) load_regs(kt + 1);

        const int fr = lane & 15;
        const int fk = (lane >> 4) * 8;
        short8 ah[2];
        #pragma unroll
        for (int mt = 0; mt < 2; ++mt)
            ah[mt] = *(const short8*)(const void*)&AsH[w * 32 + mt * 16 + fr][fk];
        #pragma unroll
        for (int nt = 0; nt < NT; ++nt) {
            short8 bh = *(const short8*)(const void*)&BsH[nt * 16 + fr][fk];
            #pragma unroll
            for (int mt = 0; mt < 2; ++mt)
                acc[mt][nt] = __builtin_amdgcn_mfma_f32_16x16x32_bf16(ah[mt], bh, acc[mt][nt], 0, 0, 0);
        }
        __syncthreads();
    }

    const int fr = lane & 15;
    const int fq = lane >> 4;
    #pragma unroll
    for (int mt = 0; mt < 2; ++mt)
        #pragma unroll
        for (int nt = 0; nt < NT; ++nt) {
            int col = nt * 16 + fr;
            if (col < FP) {
                #pragma unroll
                for (int r = 0; r < 4; ++r) {
                    int row = brow + w * 32 + mt * 16 + fq * 4 + r;
                    if (row < M) Hb[(size_t)row * FP + col] = bf16_rne(acc[mt][nt][r]);
                }
            }
        }
}

// ---------------------------------------------------------------------------
// Fused aggregation + bias + activation, bf16 H gather, sub-wave per node.
// Output (KPOUT>0): bf16 hi ONLY (1-term GEMM input). KPOUT==0: f32 out.
// ---------------------------------------------------------------------------
template <int ACT, int F, int FP, int KPOUT, int SW>
__global__ __launch_bounds__(256) void agg_act(const ushort* __restrict__ Hb,
                                               const int* __restrict__ row_start,
                                               const int* __restrict__ esrc,
                                               const float* __restrict__ bias,
                                               float* __restrict__ outF,
                                               ushort* __restrict__ ohi) {
    constexpr int CH = FP / 8;
    constexpr int NPB = 256 / SW;
    static_assert(CH <= SW, "chunks must fit sub-wave");

    const int t = threadIdx.x;
    const int sub = t / SW;
    const int subl = t - sub * SW;
    const int v = blockIdx.x * NPB + sub;
    if (v >= N_NODES) return;

    const int e0 = row_start[v];
    const int e1 = row_start[v + 1];
    const bool al = subl < CH;
    const uint4v* Hc = (const uint4v*)Hb;

    float a[8] = {0.f, 0.f, 0.f, 0.f, 0.f, 0.f, 0.f, 0.f};

    #define ACCUM(rr)                                            \
        {                                                        \
            _Pragma("unroll")                                    \
            for (int k = 0; k < 4; ++k) {                        \
                uint u = (rr)[k];                                \
                a[2 * k]     += __uint_as_float(u << 16);        \
                a[2 * k + 1] += __uint_as_float(u & 0xFFFF0000u);\
            }                                                    \
        }

    int e = e0;
    for (; e + 8 <= e1; e += 8) {
        int s0 = esrc[e + 0], s1 = esrc[e + 1], s2 = esrc[e + 2], s3 = esrc[e + 3];
        int s4 = esrc[e + 4], s5 = esrc[e + 5], s6 = esrc[e + 6], s7 = esrc[e + 7];
        if (al) {
            uint4v r0 = Hc[(size_t)s0 * CH + subl];
            uint4v r1 = Hc[(size_t)s1 * CH + subl];
            uint4v r2 = Hc[(size_t)s2 * CH + subl];
            uint4v r3 = Hc[(size_t)s3 * CH + subl];
            uint4v r4 = Hc[(size_t)s4 * CH + subl];
            uint4v r5 = Hc[(size_t)s5 * CH + subl];
            uint4v r6 = Hc[(size_t)s6 * CH + subl];
            uint4v r7 = Hc[(size_t)s7 * CH + subl];
            ACCUM(r0) ACCUM(r1) ACCUM(r2) ACCUM(r3)
            ACCUM(r4) ACCUM(r5) ACCUM(r6) ACCUM(r7)
        }
    }
    if (e + 4 <= e1) {
        int s0 = esrc[e + 0], s1 = esrc[e + 1], s2 = esrc[e + 2], s3 = esrc[e + 3];
        if (al) {
            uint4v r0 = Hc[(size_t)s0 * CH + subl];
            uint4v r1 = Hc[(size_t)s1 * CH + subl];
            uint4v r2 = Hc[(size_t)s2 * CH + subl];
            uint4v r3 = Hc[(size_t)s3 * CH + subl];
            ACCUM(r0) ACCUM(r1) ACCUM(r2) ACCUM(r3)
        }
        e += 4;
    }
    for (; e < e1; ++e) {
        int s = esrc[e];
        if (al) {
            uint4v r = Hc[(size_t)s * CH + subl];
            ACCUM(r)
        }
    }
    #undef ACCUM

    const int jb = subl * 8;
    #pragma unroll
    for (int k = 0; k < 8; ++k) {
        int j = jb + k;
        a[k] += (al && j < F) ? bias[j] : 0.f;
    }

    float res[8];
    if (ACT == 0) {
        #pragma unroll
        for (int k = 0; k < 8; ++k)
            res[k] = (a[k] >= 0.f) ? a[k] : 0.01f * a[k];
    } else {
        float m = -INFINITY;
        #pragma unroll
        for (int k = 0; k < 8; ++k) {
            int j = jb + k;
            if (al && j < F) m = fmaxf(m, a[k]);
        }
        if (SW > 1) {
            #pragma unroll
            for (int off = SW / 2; off > 0; off >>= 1) m = fmaxf(m, __shfl_xor(m, off));
        }
        float p[8];
        float s = 0.f;
        #pragma unroll
        for (int k = 0; k < 8; ++k) {
            int j = jb + k;
            if (al && j < F) { p[k] = expf(a[k] - m); s += p[k]; } else p[k] = 0.f;
        }
        if (SW > 1) {
            #pragma unroll
            for (int off = SW / 2; off > 0; off >>= 1) s += __shfl_xor(s, off);
        }
        if (ACT == 1) {
            float inv = 1.f / s;
            #pragma unroll
            for (int k = 0; k < 8; ++k) res[k] = p[k] * inv;
        } else {
            float ls = logf(s);
            #pragma unroll
            for (int k = 0; k < 8; ++k) res[k] = a[k] - m - ls;
        }
    }

    if (KPOUT == 0) {
        float* orow = outF + (size_t)v * F;
        #pragma unroll
        for (int k = 0; k < 8; ++k) {
            int j = jb + k;
            if (al && j < F) orow[j] = res[k];
        }
    } else {
        if (jb < KPOUT) {
            u16x4 h4a = {0, 0, 0, 0}, h4b = {0, 0, 0, 0};
            #pragma unroll
            for (int k = 0; k < 4; ++k) {
                int j = jb + k;
                h4a[k] = bf16_rne((j < F) ? res[k] : 0.f);
            }
            #pragma unroll
            for (int k = 0; k < 4; ++k) {
                int j = jb + 4 + k;
                h4b[k] = bf16_rne((j < F) ? res[4 + k] : 0.f);
            }
            size_t o = (size_t)v * KPOUT + jb;
            *(u16x4*)(void*)(ohi + o) = h4a;
            *(u16x4*)(void*)(ohi + o + 4) = h4b;
        }
    }
}

// ---------------------------------------------------------------------------
// Host launch
// ---------------------------------------------------------------------------
static inline size_t align_up(size_t x, size_t a) { return (x + a - 1) & ~(a - 1); }

extern "C" void kernel_launch(void* const* d_in, const int* in_sizes, int n_in,
                              void* d_out, int out_size, void* d_ws, size_t ws_size,
                              hipStream_t stream) {
    const float* features = (const float*)d_in[0];
    const int* src = (const int*)d_in[1];
    const int* dst = (const int*)d_in[2];
    const float* W[6];
    const float* b[6];
    for (int l = 0; l < 6; ++l) {
        W[l] = (const float*)d_in[3 + 2 * l];
        b[l] = (const float*)d_in[4 + 2 * l];
    }

    const int fout[6] = {200, 150, 100, 50, 25, 3};
    const int KPin[6] = {320, 224, 160, 128, 64, 32};
    const int NPl[6]  = {208, 160, 112, 64, 32, 16};   // NT*16
    const int FPl[6]  = {200, 152, 104, 56, 32, 8};    // bf16 H row stride

    // workspace layout
    char* ws = (char*)d_ws;
    size_t off = 0;
    int* row_start  = (int*)(ws + off); off = align_up(off + (N_NODES + 1) * sizeof(int), 256);
    int* cursor     = (int*)(ws + off); off = align_up(off + (N_NODES + 1) * sizeof(int), 256);
    int* esrc       = (int*)(ws + off); off = align_up(off + N_EDGES * sizeof(int), 256);
    int* blockState = (int*)(ws + off); off = align_up(off + 64 * sizeof(int), 256);
    ushort* Wthi[6];
    ushort* Wtlo[6];
    for (int l = 0; l < 6; ++l) {
        Wthi[l] = (ushort*)(ws + off); off = align_up(off + (size_t)NPl[l] * KPin[l] * 2, 256);
        Wtlo[l] = (ushort*)(ws + off); off = align_up(off + (size_t)NPl[l] * KPin[l] * 2, 256);
    }
    ushort* Xhi = (ushort*)(ws + off); off = align_up(off + (size_t)N_NODES * 320 * 2, 256);
    ushort* Xlo = (ushort*)(ws + off); off = align_up(off + (size_t)N_NODES * 320 * 2, 256);
    ushort* Hb  = (ushort*)(ws + off); off = align_up(off + (size_t)N_NODES * 200 * 2, 256);
    (void)ws_size;

    // --- fused setup: zero cursor/blockState + convert W + convert features ---
    {
        WtDescs wd;
        const int fin[6] = {300, 200, 150, 100, 50, 25};
        for (int l = 0; l < 6; ++l)
            wd.d[l] = WtDesc{W[l], Wthi[l], Wtlo[l], fin[l], fout[l], KPin[l], NPl[l]};
        setup_fused<<<2116 + (N_NODES * 80 + 255) / 256, 256, 0, stream>>>(
            cursor, blockState, wd, features, Xhi, Xlo);
    }

    // --- CSR build: count -> lookback scan -> fill ---
    count_kernel<<<(N_EDGES + 255) / 256, 256, 0, stream>>>(dst, cursor, N_EDGES);
    scan_lookback<<<(N_NODES + 1023) / 1024, 256, 0, stream>>>(cursor, row_start, cursor,
                                                               blockState, N_NODES, N_EDGES);
    fill_kernel<<<(N_EDGES + 255) / 256, 256, 0, stream>>>(src, dst, cursor, esrc, N_EDGES);

    const int gy = (N_NODES + 127) / 128;  // 391

    // L1 (3-term split): SW=32 (CH=25)
    gemm_split<320, 13><<<gy, 256, 0, stream>>>(Xhi, Xlo, Wthi[0], Wtlo[0], Hb, N_NODES, FPl[0]);
    agg_act<0, 200, 200, 224, 32><<<(N_NODES + 7) / 8, 256, 0, stream>>>(Hb, row_start, esrc, b[0], nullptr, Xhi);

    // L2-L6 (1-term bf16)
    gemm_bf16<224, 10><<<gy, 256, 0, stream>>>(Xhi, Wthi[1], Hb, N_NODES, FPl[1]);
    agg_act<1, 150, 152, 160, 32><<<(N_NODES + 7) / 8, 256, 0, stream>>>(Hb, row_start, esrc, b[1], nullptr, Xhi);

    gemm_bf16<160, 7><<<gy, 256, 0, stream>>>(Xhi, Wthi[2], Hb, N_NODES, FPl[2]);
    agg_act<0, 100, 104, 128, 16><<<(N_NODES + 15) / 16, 256, 0, stream>>>(Hb, row_start, esrc, b[2], nullptr, Xhi);

    gemm_bf16<128, 4><<<gy, 256, 0, stream>>>(Xhi, Wthi[3], Hb, N_NODES, FPl[3]);
    agg_act<1, 50, 56, 64, 8><<<(N_NODES + 31) / 32, 256, 0, stream>>>(Hb, row_start, esrc, b[3], nullptr, Xhi);

    gemm_bf16<64, 2><<<gy, 256, 0, stream>>>(Xhi, Wthi[4], Hb, N_NODES, FPl[4]);
    agg_act<0, 25, 32, 32, 4><<<(N_NODES + 63) / 64, 256, 0, stream>>>(Hb, row_start, esrc, b[4], nullptr, Xhi);

    gemm_bf16<32, 1><<<gy, 256, 0, stream>>>(Xhi, Wthi[5], Hb, N_NODES, FPl[5]);
    agg_act<2, 3, 8, 0, 1><<<(N_NODES + 255) / 256, 256, 0, stream>>>(Hb, row_start, esrc, b[5], (float*)d_out, nullptr);

    (void)out_size; (void)n_in; (void)in_sizes;
}

// Round 9
// 242.025 us; speedup vs baseline: 3.2067x; 1.0804x over previous
//
#include <hip/hip_runtime.h>
#include <math.h>

#define N_NODES 50000
#define N_EDGES 262144

using short8  = __attribute__((ext_vector_type(8))) short;
using f32x4   = __attribute__((ext_vector_type(4))) float;
using u16x4   = __attribute__((ext_vector_type(4))) unsigned short;
using u16x8   = __attribute__((ext_vector_type(8))) unsigned short;
using uint4v  = __attribute__((ext_vector_type(4))) unsigned int;

// ---------------------------------------------------------------------------
// bf16 helpers (RNE)
// ---------------------------------------------------------------------------
__device__ __forceinline__ ushort bf16_rne(float x) {
    uint u = __float_as_uint(x);
    uint r = (u + 0x7FFFu + ((u >> 16) & 1u)) >> 16;
    return (ushort)r;
}

struct WtDesc { const float* W; ushort* hi; int K, N, KP, NP; };
struct WtDescs { WtDesc d[6]; };

// ---------------------------------------------------------------------------
// Fused setup: zero cursor+blockState | convert W (hi) | convert features (hi)
// blocks [0,196): zero; [196,2116): convert_w; [2116, 2116+7813): convert_x
// ---------------------------------------------------------------------------
__global__ __launch_bounds__(256) void setup_fused(int* __restrict__ cursor,
                                                   int* __restrict__ blockState,
                                                   WtDescs all,
                                                   const float* __restrict__ X,
                                                   ushort* __restrict__ hi) {
    const int b = blockIdx.x;
    const int t = threadIdx.x;
    if (b < 196) {
        int i = b * 256 + t;
        if (i < N_NODES) cursor[i] = 0;
        if (b == 0 && t < 64) blockState[t] = 0;
    } else if (b < 2116) {
        int bb = b - 196;
        WtDesc d = all.d[bb / 320];
        int total = d.NP * d.KP;
        for (int idx = (bb % 320) * 256 + t; idx < total; idx += 320 * 256) {
            int n = idx / d.KP;
            int k = idx - n * d.KP;
            float v = (n < d.N && k < d.K) ? d.W[(size_t)k * d.N + n] : 0.f;
            d.hi[idx] = bf16_rne(v);
        }
    } else {
        int idx = (b - 2116) * 256 + t;       // N_NODES*40 ushort8 jobs
        if (idx >= N_NODES * 40) return;
        int row = idx / 40;
        int c = idx - row * 40;               // 8-col chunk
        u16x8 h8 = {0, 0, 0, 0, 0, 0, 0, 0};
        const float* xr = X + (size_t)row * 300 + c * 8;
        if (c < 37) {
            float4 v0 = *(const float4*)(const void*)(xr);
            float4 v1 = *(const float4*)(const void*)(xr + 4);
            h8[0] = bf16_rne(v0.x); h8[1] = bf16_rne(v0.y);
            h8[2] = bf16_rne(v0.z); h8[3] = bf16_rne(v0.w);
            h8[4] = bf16_rne(v1.x); h8[5] = bf16_rne(v1.y);
            h8[6] = bf16_rne(v1.z); h8[7] = bf16_rne(v1.w);
        } else if (c == 37) {
            float4 v0 = *(const float4*)(const void*)(xr);  // cols 296..299
            h8[0] = bf16_rne(v0.x); h8[1] = bf16_rne(v0.y);
            h8[2] = bf16_rne(v0.z); h8[3] = bf16_rne(v0.w);
        }
        *(u16x8*)(void*)(hi + (size_t)row * 320 + c * 8) = h8;
    }
}

// ---------------------------------------------------------------------------
// CSR build
// ---------------------------------------------------------------------------
__global__ void count_kernel(const int* __restrict__ dst, int* __restrict__ deg, int E) {
    int e = blockIdx.x * 256 + threadIdx.x;
    if (e < E) atomicAdd(&deg[dst[e]], 1);
}

// single-kernel decoupled-lookback exclusive scan (49 blocks x 1024 elems)
__global__ __launch_bounds__(256) void scan_lookback(const int* __restrict__ deg,
                                                     int* __restrict__ row_start,
                                                     int* __restrict__ cursor,
                                                     int* __restrict__ blockState,
                                                     int n, int total) {
    __shared__ int wsum[4];
    __shared__ int s_off;
    const int b = blockIdx.x;
    const int t = threadIdx.x;
    const int i0 = b * 1024 + t * 4;
    int x0 = 0, x1 = 0, x2 = 0, x3 = 0;
    if (i0 + 3 < n) {
        int4 v = *(const int4*)(const void*)(deg + i0);
        x0 = v.x; x1 = v.y; x2 = v.z; x3 = v.w;
    } else {
        if (i0 + 0 < n) x0 = deg[i0 + 0];
        if (i0 + 1 < n) x1 = deg[i0 + 1];
        if (i0 + 2 < n) x2 = deg[i0 + 2];
        if (i0 + 3 < n) x3 = deg[i0 + 3];
    }
    int s = x0 + x1 + x2 + x3;
    int lane = t & 63;
    int wid = t >> 6;
    int incl = s;
    #pragma unroll
    for (int off = 1; off < 64; off <<= 1) {
        int u = __shfl_up(incl, off);
        if (lane >= off) incl += u;
    }
    if (lane == 63) wsum[wid] = incl;
    __syncthreads();
    int woff = 0;
    #pragma unroll
    for (int k = 0; k < 4; ++k)
        if (k < wid) woff += wsum[k];
    int texcl = woff + incl - s;

    if (t == 0) {
        int bs = wsum[0] + wsum[1] + wsum[2] + wsum[3];
        atomicExch(&blockState[b], (bs << 2) | 1);
        int off = 0;
        for (int pb = b - 1; pb >= 0; --pb) {
            int st;
            do { st = atomicAdd(&blockState[pb], 0); } while ((st & 3) == 0);
            off += (st >> 2);
            if ((st & 3) == 2) break;
        }
        atomicExch(&blockState[b], ((off + bs) << 2) | 2);
        s_off = off;
    }
    __syncthreads();
    int off = s_off;

    if (i0 + 3 < n) {
        int4 o;
        o.x = off + texcl;
        o.y = off + texcl + x0;
        o.z = off + texcl + x0 + x1;
        o.w = off + texcl + x0 + x1 + x2;
        *(int4*)(void*)(row_start + i0) = o;
        *(int4*)(void*)(cursor + i0) = o;
    } else {
        int vals[4] = {off + texcl, off + texcl + x0, off + texcl + x0 + x1,
                       off + texcl + x0 + x1 + x2};
        #pragma unroll
        for (int k = 0; k < 4; ++k)
            if (i0 + k < n) { row_start[i0 + k] = vals[k]; cursor[i0 + k] = vals[k]; }
    }
    if (b == 0 && t == 0) row_start[n] = total;
}

__global__ void fill_kernel(const int* __restrict__ src, const int* __restrict__ dst,
                            int* __restrict__ cursor, int* __restrict__ esrc, int E) {
    int e = blockIdx.x * 256 + threadIdx.x;
    if (e < E) {
        int d = dst[e];
        int pos = atomicAdd(&cursor[d], 1);
        esrc[pos] = src[e];
    }
}

// ---------------------------------------------------------------------------
// 1-term bf16 MFMA GEMM (all layers). H out bf16, stride FP.
// Full-N per block, register-prefetch pipeline, A fetched once per layer.
// ---------------------------------------------------------------------------
template <int KP, int NT>
__global__ __launch_bounds__(256) void gemm_bf16(const ushort* __restrict__ Ahi,
                                                 const ushort* __restrict__ Bhi,
                                                 ushort* __restrict__ Hb, int M, int FP) {
    __shared__ __align__(16) ushort AsH[128][40];
    __shared__ __align__(16) ushort BsH[NT * 16][40];

    constexpr int NK = KP / 32;
    constexpr int BCH = (NT * 64 + 255) / 256;

    const int tid = threadIdx.x;
    const int lane = tid & 63;
    const int w = tid >> 6;
    const int brow = blockIdx.x * 128;

    f32x4 acc[2][NT];
    #pragma unroll
    for (int mt = 0; mt < 2; ++mt)
        #pragma unroll
        for (int nt = 0; nt < NT; ++nt)
            acc[mt][nt] = (f32x4){0.f, 0.f, 0.f, 0.f};

    const int ar = tid >> 1;
    const int aq = (tid & 1) * 2;
    const bool arow_ok = (brow + ar) < M;
    const size_t arow_off = (size_t)(brow + ar) * KP;

    const short8 zz = {0, 0, 0, 0, 0, 0, 0, 0};
    short8 rAh[2], rBh[BCH];

    auto load_regs = [&](int kt) {
        const int k0 = kt * 32;
        #pragma unroll
        for (int qq = 0; qq < 2; ++qq) {
            int q = aq + qq;
            rAh[qq] = arow_ok ? *(const short8*)(const void*)(Ahi + arow_off + k0 + q * 8) : zz;
        }
        #pragma unroll
        for (int c = 0; c < BCH; ++c) {
            int i = tid + c * 256;
            if (i < NT * 64) {
                int r = i >> 2;
                int q = i & 3;
                rBh[c] = *(const short8*)(const void*)(Bhi + (size_t)r * KP + k0 + q * 8);
            }
        }
    };
    auto write_lds = [&]() {
        #pragma unroll
        for (int qq = 0; qq < 2; ++qq) {
            int q = aq + qq;
            *(short8*)(void*)&AsH[ar][q * 8] = rAh[qq];
        }
        #pragma unroll
        for (int c = 0; c < BCH; ++c) {
            int i = tid + c * 256;
            if (i < NT * 64) {
                int r = i >> 2;
                int q = i & 3;
                *(short8*)(void*)&BsH[r][q * 8] = rBh[c];
            }
        }
    };

    load_regs(0);
    for (int kt = 0; kt < NK; ++kt) {
        write_lds();
        __syncthreads();
        if (kt + 1 < NK) load_regs(kt + 1);

        const int fr = lane & 15;
        const int fk = (lane >> 4) * 8;
        short8 ah[2];
        #pragma unroll
        for (int mt = 0; mt < 2; ++mt)
            ah[mt] = *(const short8*)(const void*)&AsH[w * 32 + mt * 16 + fr][fk];
        #pragma unroll
        for (int nt = 0; nt < NT; ++nt) {
            short8 bh = *(const short8*)(const void*)&BsH[nt * 16 + fr][fk];
            #pragma unroll
            for (int mt = 0; mt < 2; ++mt)
                acc[mt][nt] = __builtin_amdgcn_mfma_f32_16x16x32_bf16(ah[mt], bh, acc[mt][nt], 0, 0, 0);
        }
        __syncthreads();
    }

    const int fr = lane & 15;
    const int fq = lane >> 4;
    #pragma unroll
    for (int mt = 0; mt < 2; ++mt)
        #pragma unroll
        for (int nt = 0; nt < NT; ++nt) {
            int col = nt * 16 + fr;
            if (col < FP) {
                #pragma unroll
                for (int r = 0; r < 4; ++r) {
                    int row = brow + w * 32 + mt * 16 + fq * 4 + r;
                    if (row < M) Hb[(size_t)row * FP + col] = bf16_rne(acc[mt][nt][r]);
                }
            }
        }
}

// ---------------------------------------------------------------------------
// Fused aggregation + bias + activation, bf16 H gather, sub-wave per node.
// Output (KPOUT>0): bf16 hi. KPOUT==0: f32 out.
// ---------------------------------------------------------------------------
template <int ACT, int F, int FP, int KPOUT, int SW>
__global__ __launch_bounds__(256) void agg_act(const ushort* __restrict__ Hb,
                                               const int* __restrict__ row_start,
                                               const int* __restrict__ esrc,
                                               const float* __restrict__ bias,
                                               float* __restrict__ outF,
                                               ushort* __restrict__ ohi) {
    constexpr int CH = FP / 8;
    constexpr int NPB = 256 / SW;
    static_assert(CH <= SW, "chunks must fit sub-wave");

    const int t = threadIdx.x;
    const int sub = t / SW;
    const int subl = t - sub * SW;
    const int v = blockIdx.x * NPB + sub;
    if (v >= N_NODES) return;

    const int e0 = row_start[v];
    const int e1 = row_start[v + 1];
    const bool al = subl < CH;
    const uint4v* Hc = (const uint4v*)Hb;

    float a[8] = {0.f, 0.f, 0.f, 0.f, 0.f, 0.f, 0.f, 0.f};

    #define ACCUM(rr)                                            \
        {                                                        \
            _Pragma("unroll")                                    \
            for (int k = 0; k < 4; ++k) {                        \
                uint u = (rr)[k];                                \
                a[2 * k]     += __uint_as_float(u << 16);        \
                a[2 * k + 1] += __uint_as_float(u & 0xFFFF0000u);\
            }                                                    \
        }

    int e = e0;
    for (; e + 8 <= e1; e += 8) {
        int s0 = esrc[e + 0], s1 = esrc[e + 1], s2 = esrc[e + 2], s3 = esrc[e + 3];
        int s4 = esrc[e + 4], s5 = esrc[e + 5], s6 = esrc[e + 6], s7 = esrc[e + 7];
        if (al) {
            uint4v r0 = Hc[(size_t)s0 * CH + subl];
            uint4v r1 = Hc[(size_t)s1 * CH + subl];
            uint4v r2 = Hc[(size_t)s2 * CH + subl];
            uint4v r3 = Hc[(size_t)s3 * CH + subl];
            uint4v r4 = Hc[(size_t)s4 * CH + subl];
            uint4v r5 = Hc[(size_t)s5 * CH + subl];
            uint4v r6 = Hc[(size_t)s6 * CH + subl];
            uint4v r7 = Hc[(size_t)s7 * CH + subl];
            ACCUM(r0) ACCUM(r1) ACCUM(r2) ACCUM(r3)
            ACCUM(r4) ACCUM(r5) ACCUM(r6) ACCUM(r7)
        }
    }
    if (e + 4 <= e1) {
        int s0 = esrc[e + 0], s1 = esrc[e + 1], s2 = esrc[e + 2], s3 = esrc[e + 3];
        if (al) {
            uint4v r0 = Hc[(size_t)s0 * CH + subl];
            uint4v r1 = Hc[(size_t)s1 * CH + subl];
            uint4v r2 = Hc[(size_t)s2 * CH + subl];
            uint4v r3 = Hc[(size_t)s3 * CH + subl];
            ACCUM(r0) ACCUM(r1) ACCUM(r2) ACCUM(r3)
        }
        e += 4;
    }
    for (; e < e1; ++e) {
        int s = esrc[e];
        if (al) {
            uint4v r = Hc[(size_t)s * CH + subl];
            ACCUM(r)
        }
    }
    #undef ACCUM

    const int jb = subl * 8;
    #pragma unroll
    for (int k = 0; k < 8; ++k) {
        int j = jb + k;
        a[k] += (al && j < F) ? bias[j] : 0.f;
    }

    float res[8];
    if (ACT == 0) {
        #pragma unroll
        for (int k = 0; k < 8; ++k)
            res[k] = (a[k] >= 0.f) ? a[k] : 0.01f * a[k];
    } else {
        float m = -INFINITY;
        #pragma unroll
        for (int k = 0; k < 8; ++k) {
            int j = jb + k;
            if (al && j < F) m = fmaxf(m, a[k]);
        }
        if (SW > 1) {
            #pragma unroll
            for (int off = SW / 2; off > 0; off >>= 1) m = fmaxf(m, __shfl_xor(m, off));
        }
        float p[8];
        float s = 0.f;
        #pragma unroll
        for (int k = 0; k < 8; ++k) {
            int j = jb + k;
            if (al && j < F) { p[k] = expf(a[k] - m); s += p[k]; } else p[k] = 0.f;
        }
        if (SW > 1) {
            #pragma unroll
            for (int off = SW / 2; off > 0; off >>= 1) s += __shfl_xor(s, off);
        }
        if (ACT == 1) {
            float inv = 1.f / s;
            #pragma unroll
            for (int k = 0; k < 8; ++k) res[k] = p[k] * inv;
        } else {
            float ls = logf(s);
            #pragma unroll
            for (int k = 0; k < 8; ++k) res[k] = a[k] - m - ls;
        }
    }

    if (KPOUT == 0) {
        float* orow = outF + (size_t)v * F;
        #pragma unroll
        for (int k = 0; k < 8; ++k) {
            int j = jb + k;
            if (al && j < F) orow[j] = res[k];
        }
    } else {
        if (jb < KPOUT) {
            u16x4 h4a = {0, 0, 0, 0}, h4b = {0, 0, 0, 0};
            #pragma unroll
            for (int k = 0; k < 4; ++k) {
                int j = jb + k;
                h4a[k] = bf16_rne((j < F) ? res[k] : 0.f);
            }
            #pragma unroll
            for (int k = 0; k < 4; ++k) {
                int j = jb + 4 + k;
                h4b[k] = bf16_rne((j < F) ? res[4 + k] : 0.f);
            }
            size_t o = (size_t)v * KPOUT + jb;
            *(u16x4*)(void*)(ohi + o) = h4a;
            *(u16x4*)(void*)(ohi + o + 4) = h4b;
        }
    }
}

// ---------------------------------------------------------------------------
// Host launch
// ---------------------------------------------------------------------------
static inline size_t align_up(size_t x, size_t a) { return (x + a - 1) & ~(a - 1); }

extern "C" void kernel_launch(void* const* d_in, const int* in_sizes, int n_in,
                              void* d_out, int out_size, void* d_ws, size_t ws_size,
                              hipStream_t stream) {
    const float* features = (const float*)d_in[0];
    const int* src = (const int*)d_in[1];
    const int* dst = (const int*)d_in[2];
    const float* W[6];
    const float* b[6];
    for (int l = 0; l < 6; ++l) {
        W[l] = (const float*)d_in[3 + 2 * l];
        b[l] = (const float*)d_in[4 + 2 * l];
    }

    const int fout[6] = {200, 150, 100, 50, 25, 3};
    const int KPin[6] = {320, 224, 160, 128, 64, 32};
    const int NPl[6]  = {208, 160, 112, 64, 32, 16};   // NT*16
    const int FPl[6]  = {200, 152, 104, 56, 32, 8};    // bf16 H row stride

    // workspace layout
    char* ws = (char*)d_ws;
    size_t off = 0;
    int* row_start  = (int*)(ws + off); off = align_up(off + (N_NODES + 1) * sizeof(int), 256);
    int* cursor     = (int*)(ws + off); off = align_up(off + (N_NODES + 1) * sizeof(int), 256);
    int* esrc       = (int*)(ws + off); off = align_up(off + N_EDGES * sizeof(int), 256);
    int* blockState = (int*)(ws + off); off = align_up(off + 64 * sizeof(int), 256);
    ushort* Wthi[6];
    for (int l = 0; l < 6; ++l) {
        Wthi[l] = (ushort*)(ws + off); off = align_up(off + (size_t)NPl[l] * KPin[l] * 2, 256);
    }
    ushort* Xhi = (ushort*)(ws + off); off = align_up(off + (size_t)N_NODES * 320 * 2, 256);
    ushort* Hb  = (ushort*)(ws + off); off = align_up(off + (size_t)N_NODES * 200 * 2, 256);
    (void)ws_size;

    // --- fused setup ---
    {
        WtDescs wd;
        const int fin[6] = {300, 200, 150, 100, 50, 25};
        for (int l = 0; l < 6; ++l)
            wd.d[l] = WtDesc{W[l], Wthi[l], fin[l], fout[l], KPin[l], NPl[l]};
        setup_fused<<<2116 + (N_NODES * 40 + 255) / 256, 256, 0, stream>>>(
            cursor, blockState, wd, features, Xhi);
    }

    // --- CSR build ---
    count_kernel<<<(N_EDGES + 255) / 256, 256, 0, stream>>>(dst, cursor, N_EDGES);
    scan_lookback<<<(N_NODES + 1023) / 1024, 256, 0, stream>>>(cursor, row_start, cursor,
                                                               blockState, N_NODES, N_EDGES);
    fill_kernel<<<(N_EDGES + 255) / 256, 256, 0, stream>>>(src, dst, cursor, esrc, N_EDGES);

    const int gy = (N_NODES + 127) / 128;  // 391

    gemm_bf16<320, 13><<<gy, 256, 0, stream>>>(Xhi, Wthi[0], Hb, N_NODES, FPl[0]);
    agg_act<0, 200, 200, 224, 32><<<(N_NODES + 7) / 8, 256, 0, stream>>>(Hb, row_start, esrc, b[0], nullptr, Xhi);

    gemm_bf16<224, 10><<<gy, 256, 0, stream>>>(Xhi, Wthi[1], Hb, N_NODES, FPl[1]);
    agg_act<1, 150, 152, 160, 32><<<(N_NODES + 7) / 8, 256, 0, stream>>>(Hb, row_start, esrc, b[1], nullptr, Xhi);

    gemm_bf16<160, 7><<<gy, 256, 0, stream>>>(Xhi, Wthi[2], Hb, N_NODES, FPl[2]);
    agg_act<0, 100, 104, 128, 16><<<(N_NODES + 15) / 16, 256, 0, stream>>>(Hb, row_start, esrc, b[2], nullptr, Xhi);

    gemm_bf16<128, 4><<<gy, 256, 0, stream>>>(Xhi, Wthi[3], Hb, N_NODES, FPl[3]);
    agg_act<1, 50, 56, 64, 8><<<(N_NODES + 31) / 32, 256, 0, stream>>>(Hb, row_start, esrc, b[3], nullptr, Xhi);

    gemm_bf16<64, 2><<<gy, 256, 0, stream>>>(Xhi, Wthi[4], Hb, N_NODES, FPl[4]);
    agg_act<0, 25, 32, 32, 4><<<(N_NODES + 63) / 64, 256, 0, stream>>>(Hb, row_start, esrc, b[4], nullptr, Xhi);

    gemm_bf16<32, 1><<<gy, 256, 0, stream>>>(Xhi, Wthi[5], Hb, N_NODES, FPl[5]);
    agg_act<2, 3, 8, 0, 1><<<(N_NODES + 255) / 256, 256, 0, stream>>>(Hb, row_start, esrc, b[5], (float*)d_out, nullptr);

    (void)out_size; (void)n_in; (void)in_sizes;
}